// Round 7
// baseline (3769.230 us; speedup 1.0000x reference)
//
#include <hip/hip_runtime.h>
#include <stdint.h>

typedef unsigned short u16;
typedef __attribute__((ext_vector_type(8))) __bf16 bf16x8;
typedef __attribute__((ext_vector_type(4))) float f32x4;

// dims
#define Bb 4
#define Ll 96
#define Nn 200
#define Dd 128
#define Hh 8
#define Tt 76800   // B*N*L
#define RSEQ 800   // B*N
#define PREDp 96

__device__ __forceinline__ u16 f2b(float f) {
  union { float f; uint32_t u; } c; c.f = f;
  return (u16)((c.u + 0x7FFFu + ((c.u >> 16) & 1u)) >> 16);
}
__device__ __forceinline__ float b2f(u16 h) {
  union { uint32_t u; float f; } c; c.u = ((uint32_t)h) << 16;
  return c.f;
}

// ============ workhorse GEMM: C[R,N] = A[R,K] @ Bt[N,K]^T ============
// DUAL=1: dual-bf16 planes (hi + lo at +Pl elems); computes Ah*Bh + Ah*Bl + Al*Bh (≈ fp32).
// AF32=1 (requires DUAL=1): A is fp32; hi/lo split happens during LDS staging.
// GATH=1: A rows gathered via rowidx (row count = *cntp); C rows dense.
// GATH=2: A rows dense (count = *cntp); C rows scattered via rowidx with gate-weighted
//         atomicAdd (split-K safe; bias applied only when klo==0).
#define LDKV 72

template<int MODE, int DUAL, int AF32, int GATH>
// MODE: 0 linear, 1 relu, 2 gate-weighted accumulate, 3 atomic split-K
__global__ __launch_bounds__(256) void gemm_bf16(
    const u16* __restrict__ A, size_t aPl, const u16* __restrict__ Bt, size_t bPl,
    const float* __restrict__ bias, float* Cf, u16* Cb, size_t cPl,
    int R, int K, int N, int kchunk,
    const float* __restrict__ G, int expert, int accum,
    const int* __restrict__ rowidx, const int* __restrict__ cntp)
{
  __shared__ u16 As[128 * LDKV];
  __shared__ u16 Bs[128 * LDKV];
  __shared__ u16 Asl[DUAL ? 128 * LDKV : 2];
  __shared__ u16 Bsl[DUAL ? 128 * LDKV : 2];
  const int tid = threadIdx.x;
  const int bM = blockIdx.x * 128, bN = blockIdx.y * 128;
  int Reff = R;
  if (GATH) { Reff = *cntp; if (bM >= Reff) return; }
  const int klo = blockIdx.z * kchunk;
  const int khi = (K < klo + kchunk) ? K : (klo + kchunk);
  const int wave = tid >> 6, lane = tid & 63;
  const int wr = (wave >> 1) * 64, wc = (wave & 1) * 64;
  const int lr = lane & 15, kg = (lane >> 4) * 8;
  f32x4 acc[4][4];
  const f32x4 zz = {0.f, 0.f, 0.f, 0.f};
#pragma unroll
  for (int m = 0; m < 4; m++)
#pragma unroll
    for (int n = 0; n < 4; n++) acc[m][n] = zz;

  for (int k0 = klo; k0 < khi; k0 += 64) {
#pragma unroll
    for (int i = 0; i < 4; i++) {
      int v = tid + i * 256;           // 0..1023 over 128 rows x 8 chunks
      int r = v >> 3, c8 = (v & 7) * 8;
      int gr = bM + r, gc = bN + r;
      bool aok = gr < Reff;
      int ar = gr;
      if (GATH == 1) { if (aok) ar = rowidx[gr]; }
      if (AF32) {
        const float* Af = (const float*)A;
        float4 f0 = make_float4(0, 0, 0, 0), f1 = make_float4(0, 0, 0, 0);
        if (aok) {
          f0 = *(const float4*)(Af + (size_t)ar * K + k0 + c8);
          f1 = *(const float4*)(Af + (size_t)ar * K + k0 + c8 + 4);
        }
        float ff[8] = {f0.x, f0.y, f0.z, f0.w, f1.x, f1.y, f1.z, f1.w};
        union { int4 v4; u16 us[8]; } hu, lu;
#pragma unroll
        for (int j = 0; j < 8; j++) {
          u16 h = f2b(ff[j]);
          hu.us[j] = h;
          lu.us[j] = f2b(ff[j] - b2f(h));
        }
        *(int4*)(&As[r * LDKV + c8]) = hu.v4;
        *(int4*)(&Asl[r * LDKV + c8]) = lu.v4;
      } else {
        int4 av = make_int4(0, 0, 0, 0);
        if (aok) av = *(const int4*)(A + (size_t)ar * K + k0 + c8);
        *(int4*)(&As[r * LDKV + c8]) = av;
        if (DUAL) {
          int4 av2 = make_int4(0, 0, 0, 0);
          if (aok) av2 = *(const int4*)(A + aPl + (size_t)ar * K + k0 + c8);
          *(int4*)(&Asl[r * LDKV + c8]) = av2;
        }
      }
      int4 bv = make_int4(0, 0, 0, 0);
      if (gc < N) bv = *(const int4*)(Bt + (size_t)gc * K + k0 + c8);
      *(int4*)(&Bs[r * LDKV + c8]) = bv;
      if (DUAL) {
        int4 bv2 = make_int4(0, 0, 0, 0);
        if (gc < N) bv2 = *(const int4*)(Bt + bPl + (size_t)gc * K + k0 + c8);
        *(int4*)(&Bsl[r * LDKV + c8]) = bv2;
      }
    }
    __syncthreads();
#pragma unroll
    for (int kk = 0; kk < 64; kk += 32) {
      bf16x8 ah[4], bh[4], al[4], bl[4];
#pragma unroll
      for (int m = 0; m < 4; m++) ah[m] = *(const bf16x8*)(&As[(wr + m * 16 + lr) * LDKV + kk + kg]);
#pragma unroll
      for (int n = 0; n < 4; n++) bh[n] = *(const bf16x8*)(&Bs[(wc + n * 16 + lr) * LDKV + kk + kg]);
      if (DUAL) {
#pragma unroll
        for (int m = 0; m < 4; m++) al[m] = *(const bf16x8*)(&Asl[(wr + m * 16 + lr) * LDKV + kk + kg]);
#pragma unroll
        for (int n = 0; n < 4; n++) bl[n] = *(const bf16x8*)(&Bsl[(wc + n * 16 + lr) * LDKV + kk + kg]);
      }
#pragma unroll
      for (int m = 0; m < 4; m++)
#pragma unroll
        for (int n = 0; n < 4; n++) {
          acc[m][n] = __builtin_amdgcn_mfma_f32_16x16x32_bf16(ah[m], bh[n], acc[m][n], 0, 0, 0);
          if (DUAL) {
            acc[m][n] = __builtin_amdgcn_mfma_f32_16x16x32_bf16(ah[m], bl[n], acc[m][n], 0, 0, 0);
            acc[m][n] = __builtin_amdgcn_mfma_f32_16x16x32_bf16(al[m], bh[n], acc[m][n], 0, 0, 0);
          }
        }
    }
    __syncthreads();
  }

  const int row0 = bM + wr + (lane >> 4) * 4;
  const int col0 = bN + wc + (lane & 15);
#pragma unroll
  for (int m = 0; m < 4; m++) {
#pragma unroll
    for (int n = 0; n < 4; n++) {
      int col = col0 + n * 16;
      if (col >= N) continue;
#pragma unroll
      for (int r = 0; r < 4; r++) {
        int row = row0 + m * 16 + r;
        if (row >= Reff) continue;
        float v = acc[m][n][r];
        size_t ci = (size_t)row * N + col;
        if (MODE == 3) {
          atomicAdd(Cf + ci, v);
        } else {
          if (bias && !(GATH == 2 && klo > 0)) v += bias[col];
          if (MODE == 1) v = fmaxf(v, 0.f);
          if (MODE == 2) {
            if (GATH == 2) {
              int trow = rowidx[row];
              atomicAdd(Cf + (size_t)trow * N + col, v * G[trow * 4 + expert]);
            } else {
              v *= G[row * 4 + expert];
              if (accum) v += Cf[ci];
              Cf[ci] = v;
            }
          } else {
            if (Cf) Cf[ci] = v;
            if (Cb) {
              u16 h = f2b(v);
              Cb[ci] = h;
              if (cPl) Cb[cPl + ci] = f2b(v - b2f(h));
            }
          }
        }
      }
    }
  }
}

// ---------------- tiled transpose f32 -> dual bf16: Wt[bb][n][k](hi,lo) = W[bb][k][n] ----------------
// PL==0: write hi plane only.
__global__ void prep_wt_tiled(const float* __restrict__ W, u16* __restrict__ Wt,
                              int K, int N, int KP, int NP, size_t PL, size_t bstride)
{
  __shared__ float tile[32][33];
  int k0 = blockIdx.x * 32, n0 = blockIdx.y * 32;
  int bb = blockIdx.z;
  const float* Wb = W + (size_t)bb * K * N;
  u16* Wtb = Wt + (size_t)bb * bstride;
  for (int i = threadIdx.y; i < 32; i += 8) {
    int k = k0 + i, n = n0 + threadIdx.x;
    tile[i][threadIdx.x] = (k < K && n < N) ? Wb[(size_t)k * N + n] : 0.f;
  }
  __syncthreads();
  for (int i = threadIdx.y; i < 32; i += 8) {
    int n = n0 + i, k = k0 + threadIdx.x;
    if (n < NP && k < KP) {
      float v = tile[threadIdx.x][i];
      u16 h = f2b(v);
      Wtb[(size_t)n * KP + k] = h;
      if (PL) Wtb[PL + (size_t)n * KP + k] = f2b(v - b2f(h));
    }
  }
}

__global__ void copy_dual(const float* __restrict__ s, u16* __restrict__ d, int n, size_t PL) {
  int i = blockIdx.x * 256 + threadIdx.x;
  if (i < n) {
    float v = s[i];
    u16 h = f2b(v);
    d[i] = h;
    d[PL + i] = f2b(v - b2f(h));
  }
}
__global__ void zero_f32(float* p, int n) {
  int i = blockIdx.x * 256 + threadIdx.x;
  if (i < n) p[i] = 0.f;
}

// ---------------- RevIN stats per batch ----------------
__global__ __launch_bounds__(256) void revin_stats(const float* __restrict__ x, float* stats) {
  int b = blockIdx.x;
  __shared__ float ss[256], sq[256];
  float s = 0.f, q = 0.f;
  for (int i = threadIdx.x; i < Ll * Nn; i += 256) {
    float v = x[(size_t)b * Ll * Nn + i];
    s += v; q += v * v;
  }
  ss[threadIdx.x] = s; sq[threadIdx.x] = q;
  __syncthreads();
  for (int st = 128; st > 0; st >>= 1) {
    if (threadIdx.x < st) { ss[threadIdx.x] += ss[threadIdx.x + st]; sq[threadIdx.x] += sq[threadIdx.x + st]; }
    __syncthreads();
  }
  if (threadIdx.x == 0) {
    float mean = ss[0] / (float)(Ll * Nn);
    float var = sq[0] / (float)(Ll * Nn) - mean * mean;
    float sd = sqrtf(var + 1e-5f);
    stats[b] = mean; stats[4 + b] = 1.f / sd; stats[8 + b] = sd;
  }
}

// ---------------- combine vectors for the decomposed concat-proj ----------------
__global__ void calc_vecs(const float* __restrict__ embW, const float* __restrict__ embB,
                          const float* __restrict__ projW, const float* __restrict__ projB,
                          float* __restrict__ vecs)
{
  int j = threadIdx.x;  // 128
  float a = 0, b = 0, c = 0, d = 0, e = 0;
  for (int k = 0; k < 128; k++) {
    float p0 = projW[(size_t)k * 128 + j];
    float p1 = projW[(size_t)(128 + k) * 128 + j];
    a += embW[k] * p0;              // trend coeff (emb_W row 0)
    b += embW[k] * p1;              // season coeff
    c += embW[128 + k] * (p0 + p1); // tod coeff (emb_W row 1)
    d += embW[256 + k] * (p0 + p1); // dow coeff (emb_W row 2)
    e += embB[k] * (p0 + p1);
  }
  vecs[j] = a; vecs[128 + j] = b; vecs[256 + j] = c; vecs[384 + j] = d;
  vecs[512 + j] = e + projB[j];
}

// ---------------- concat qkv biases: out[layer][384] ----------------
__global__ void concat_qkvb(const float* __restrict__ bq, const float* __restrict__ bk,
                            const float* __restrict__ bv, float* __restrict__ out)
{
  int t = blockIdx.x * 128 + threadIdx.x;
  if (t >= 3 * 384) return;
  int layer = t / 384, r = t % 384, part = r / 128, col = r % 128;
  const float* src = part == 0 ? bq : (part == 1 ? bk : bv);
  out[t] = src[layer * 128 + col];
}

// ---------------- spatial input: xs[b*N+n][l] = xn (dual), zero-padded to K=128 ----------------
__global__ void xs_build(const float* __restrict__ x, const float* __restrict__ stats,
                         u16* __restrict__ xs, size_t PL)
{
  int r = blockIdx.x;          // b*200+n
  int l = threadIdx.x;         // 128
  int b = r / Nn, n = r % Nn;
  float v = 0.f;
  if (l < Ll) v = (x[((size_t)(b * Ll + l) * Nn + n)] - stats[b]) * stats[4 + b];
  u16 h = f2b(v);
  xs[(size_t)r * 128 + l] = h;
  xs[PL + (size_t)r * 128 + l] = f2b(v - b2f(h));
}

// ---------------- S=1 performer for spatial block: o = v * t/(t+1e-6), fp32 in, dual out ----------------
__global__ __launch_bounds__(128) void sp_perf(const float* __restrict__ qf, const float* __restrict__ kf,
                                               const float* __restrict__ vf, const float* __restrict__ proj,
                                               u16* __restrict__ ob, size_t PL)
{
  int r = blockIdx.x, tid = threadIdx.x;
  __shared__ float ql[128], kl[128], vl[128], ps[256];
  ql[tid] = qf[(size_t)r * 128 + tid] * 0.5f;  // dn = 16^-0.25 = 0.5
  kl[tid] = kf[(size_t)r * 128 + tid] * 0.5f;
  vl[tid] = vf[(size_t)r * 128 + tid];
  ps[tid] = proj[tid]; ps[128 + tid] = proj[128 + tid];
  __syncthreads();
  int h = tid >> 4, m = tid & 15;
  float qd = 0, kd = 0, qn = 0, kn = 0;
#pragma unroll
  for (int d = 0; d < 16; d++) {
    float qv = ql[h * 16 + d], kv_ = kl[h * 16 + d];
    qd += qv * ps[d * 16 + m]; kd += kv_ * ps[d * 16 + m];
    qn += qv * qv; kn += kv_ * kv_;
  }
  qn *= 0.5f; kn *= 0.5f;
  float qmax = qd, kmax = kd;
  for (int msk = 8; msk; msk >>= 1) {
    qmax = fmaxf(qmax, __shfl_xor(qmax, msk, 16));
    kmax = fmaxf(kmax, __shfl_xor(kmax, msk, 16));
  }
  float qp = expf(qd - qn - qmax) * 0.25f + 1e-6f;
  float kp = expf(kd - kn - kmax) * 0.25f + 1e-6f;
  float t = qp * kp;
  for (int msk = 8; msk; msk >>= 1) t += __shfl_xor(t, msk, 16);
  float f = t / (t + 1e-6f);
  float o = vl[tid] * f;
  u16 hh = f2b(o);
  ob[(size_t)r * 128 + tid] = hh;
  ob[PL + (size_t)r * 128 + tid] = f2b(o - b2f(hh));
}

// ---------------- FAVOR+ attention S=96, block = (seq, head-pair), fused qkv input ----------------
// qkv: [rows][384] fp32 (q|k|v), ao: [rows][128] fp32
// q is loaded per-owner-thread (registers); ks holds k -> kp -> output staging. LDS ~30 KB.
__global__ __launch_bounds__(256) void performer_attn2(
    const float* __restrict__ qkv, const float* __restrict__ proj, float* __restrict__ ao)
{
  __shared__ float ks[2][96 * 17];   // k, then kp, then output staging
  __shared__ float vs[2][96 * 17];
  __shared__ float kvs[2][16 * 17];
  __shared__ float ksum[2][16];
  __shared__ float red[2][96];
  __shared__ float ps[256];
  const int tid = threadIdx.x;
  const int seq = blockIdx.x >> 2, hp = blockIdx.x & 3;
  ps[tid] = proj[tid];
  // stage k,v into LDS (coalesced row segments)
#pragma unroll
  for (int i = 0; i < 3; i++) {
    int idx = tid + i * 256;            // 0..767 = 96 rows x 8 slots
    int row = idx >> 3, c4 = idx & 7;
    int hl = c4 >> 2, d0 = (c4 & 3) * 4;
    size_t gb = ((size_t)seq * 96 + row) * 384 + hp * 32 + hl * 16 + d0;
    float4 k4 = *(const float4*)(qkv + gb + 128);
    float4 v4 = *(const float4*)(qkv + gb + 256);
    int lb = row * 17 + d0;
    ks[hl][lb + 0] = k4.x * 0.5f; ks[hl][lb + 1] = k4.y * 0.5f;
    ks[hl][lb + 2] = k4.z * 0.5f; ks[hl][lb + 3] = k4.w * 0.5f;
    vs[hl][lb + 0] = v4.x; vs[hl][lb + 1] = v4.y;
    vs[hl][lb + 2] = v4.z; vs[hl][lb + 3] = v4.w;
  }
  // q straight to registers for owner threads
  const int h = tid / 96, s = tid - h * 96;   // valid for tid<192
  float q[16];
  if (tid < 192) {
    size_t qb_ = ((size_t)seq * 96 + s) * 384 + hp * 32 + h * 16;
#pragma unroll
    for (int i = 0; i < 4; i++) {
      float4 t = *(const float4*)(qkv + qb_ + i * 4);
      q[i * 4] = t.x * 0.5f; q[i * 4 + 1] = t.y * 0.5f;
      q[i * 4 + 2] = t.z * 0.5f; q[i * 4 + 3] = t.w * 0.5f;
    }
  }
  __syncthreads();
  float qd[16], kd[16], qp[16];
  float qn = 0.f, kn = 0.f;
  if (tid < 192) {
#pragma unroll
    for (int d = 0; d < 16; d++) {
      float kv = ks[h][s * 17 + d];
      qn += q[d] * q[d]; kn += kv * kv;
    }
    qn *= 0.5f; kn *= 0.5f;
#pragma unroll
    for (int m = 0; m < 16; m++) {
      float aq = 0.f, ak = 0.f;
#pragma unroll
      for (int d = 0; d < 16; d++) {
        aq += q[d] * ps[d * 16 + m];
        ak += ks[h][s * 17 + d] * ps[d * 16 + m];
      }
      qd[m] = aq; kd[m] = ak;
    }
    float km = kd[0];
#pragma unroll
    for (int m = 1; m < 16; m++) km = fmaxf(km, kd[m]);
    red[h][s] = km;
  }
  __syncthreads();
  if (tid < 192 && s < 48) red[h][s] = fmaxf(red[h][s], red[h][s + 48]);
  __syncthreads();
  if (tid < 192 && s < 24) red[h][s] = fmaxf(red[h][s], red[h][s + 24]);
  __syncthreads();
  if (tid < 192 && s < 12) red[h][s] = fmaxf(red[h][s], red[h][s + 12]);
  __syncthreads();
  if (tid < 192 && s < 6) red[h][s] = fmaxf(red[h][s], red[h][s + 6]);
  __syncthreads();
  if (tid < 192 && s < 3) red[h][s] = fmaxf(red[h][s], red[h][s + 3]);
  __syncthreads();
  if (tid < 192) {
    float kmax = fmaxf(fmaxf(red[h][0], red[h][1]), red[h][2]);
    float qmx = qd[0];
#pragma unroll
    for (int m = 1; m < 16; m++) qmx = fmaxf(qmx, qd[m]);
#pragma unroll
    for (int m = 0; m < 16; m++) {
      qp[m] = expf(qd[m] - qn - qmx) * 0.25f + 1e-6f;
      ks[h][s * 17 + m] = expf(kd[m] - kn - kmax) * 0.25f + 1e-6f;  // kp overwrites k
    }
  }
  __syncthreads();
#pragma unroll
  for (int it = 0; it < 2; it++) {
    int idx = tid + it * 256;            // 0..511 = (h,m,d)
    int hh = idx >> 8, mm = (idx >> 4) & 15, dd = idx & 15;
    float a0 = 0.f, a1 = 0.f, a2 = 0.f, a3 = 0.f;
    for (int s2 = 0; s2 < 96; s2 += 4) {
      a0 += ks[hh][(s2 + 0) * 17 + mm] * vs[hh][(s2 + 0) * 17 + dd];
      a1 += ks[hh][(s2 + 1) * 17 + mm] * vs[hh][(s2 + 1) * 17 + dd];
      a2 += ks[hh][(s2 + 2) * 17 + mm] * vs[hh][(s2 + 2) * 17 + dd];
      a3 += ks[hh][(s2 + 3) * 17 + mm] * vs[hh][(s2 + 3) * 17 + dd];
    }
    kvs[hh][mm * 17 + dd] = (a0 + a1) + (a2 + a3);
  }
  if (tid < 32) {
    int hh = tid >> 4, mm = tid & 15;
    float a0 = 0.f, a1 = 0.f, a2 = 0.f, a3 = 0.f;
    for (int s2 = 0; s2 < 96; s2 += 4) {
      a0 += ks[hh][(s2 + 0) * 17 + mm];
      a1 += ks[hh][(s2 + 1) * 17 + mm];
      a2 += ks[hh][(s2 + 2) * 17 + mm];
      a3 += ks[hh][(s2 + 3) * 17 + mm];
    }
    ksum[hh][mm] = (a0 + a1) + (a2 + a3);
  }
  __syncthreads();
  if (tid < 192) {
    float zd = 1e-6f;
#pragma unroll
    for (int m = 0; m < 16; m++) zd += qp[m] * ksum[h][m];
    float zi = 1.f / zd;
#pragma unroll
    for (int d = 0; d < 16; d++) {
      float a = 0.f;
#pragma unroll
      for (int m = 0; m < 16; m++) a += qp[m] * kvs[h][m * 17 + d];
      ks[h][s * 17 + d] = a * zi;        // reuse ks as output staging (kp dead)
    }
  }
  __syncthreads();
#pragma unroll
  for (int i = 0; i < 3; i++) {
    int idx = tid + i * 256;
    int row = idx >> 3, c4 = idx & 7;
    int hl = c4 >> 2, d0 = (c4 & 3) * 4;
    int lb = row * 17 + d0;
    float4 o;
    o.x = ks[hl][lb + 0]; o.y = ks[hl][lb + 1]; o.z = ks[hl][lb + 2]; o.w = ks[hl][lb + 3];
    *(float4*)(ao + ((size_t)seq * 96 + row) * 128 + hp * 32 + hl * 16 + d0) = o;
  }
}

// ---------------- fused residual-add + LayerNorm: dual in + f32 res -> dual out ----------------
__global__ __launch_bounds__(256) void ln_fused(const u16* __restrict__ Xin, size_t xPl,
    const float* __restrict__ Res,
    const float* __restrict__ g, const float* __restrict__ bta,
    u16* __restrict__ Out, size_t oPl, int R)
{
  int wave = threadIdx.x >> 6, lane = threadIdx.x & 63;
  int tok = blockIdx.x * 4 + wave;
  if (tok >= R) return;
  size_t bo = (size_t)tok * 128 + lane * 2;
  ushort2 h2 = *(const ushort2*)(Xin + bo);
  ushort2 l2 = *(const ushort2*)(Xin + xPl + bo);
  float2 rv = *(const float2*)(Res + bo);
  float a0 = b2f(h2.x) + b2f(l2.x) + rv.x;
  float a1 = b2f(h2.y) + b2f(l2.y) + rv.y;
  float s = a0 + a1, sq = a0 * a0 + a1 * a1;
  for (int m = 32; m; m >>= 1) { s += __shfl_xor(s, m); sq += __shfl_xor(sq, m); }
  float mean = s * (1.f / 128.f);
  float var = sq * (1.f / 128.f) - mean * mean;
  float rstd = rsqrtf(var + 1e-5f);
  float g0 = g[lane * 2], g1 = g[lane * 2 + 1], b0 = bta[lane * 2], b1 = bta[lane * 2 + 1];
  float o0 = (a0 - mean) * rstd * g0 + b0;
  float o1 = (a1 - mean) * rstd * g1 + b1;
  u16 u0 = f2b(o0), u1 = f2b(o1);
  ushort2 hh; hh.x = u0; hh.y = u1;
  ushort2 ll; ll.x = f2b(o0 - b2f(u0)); ll.y = f2b(o1 - b2f(u1));
  *(ushort2*)(Out + bo) = hh;
  *(ushort2*)(Out + oPl + bo) = ll;
}

// ---------------- MoE gate: softmax top-2 renormalized, dual-bf16 input ----------------
__global__ __launch_bounds__(256) void gate_topk(const u16* __restrict__ X, size_t xPl,
    const float* __restrict__ Wg, float* __restrict__ Gout, int R)
{
  int gid = blockIdx.x * 256 + threadIdx.x;
  int tok = gid >> 2, sub = gid & 3;
  if (tok >= R) return;
  float pr0 = 0, pr1 = 0, pr2 = 0, pr3 = 0;
  for (int d0 = 0; d0 < 32; d0 += 8) {
    size_t idx = (size_t)tok * 128 + sub * 32 + d0;
    int4 hv = *(const int4*)(X + idx);
    int4 lv = *(const int4*)(X + xPl + idx);
    const u16* hp = (const u16*)&hv;
    const u16* lp = (const u16*)&lv;
#pragma unroll
    for (int j = 0; j < 8; j++) {
      float xj = b2f(hp[j]) + b2f(lp[j]);
      float4 w = *(const float4*)(Wg + (size_t)(sub * 32 + d0 + j) * 4);
      pr0 += xj * w.x; pr1 += xj * w.y; pr2 += xj * w.z; pr3 += xj * w.w;
    }
  }
  pr0 += __shfl_xor(pr0, 1, 4); pr0 += __shfl_xor(pr0, 2, 4);
  pr1 += __shfl_xor(pr1, 1, 4); pr1 += __shfl_xor(pr1, 2, 4);
  pr2 += __shfl_xor(pr2, 1, 4); pr2 += __shfl_xor(pr2, 2, 4);
  pr3 += __shfl_xor(pr3, 1, 4); pr3 += __shfl_xor(pr3, 2, 4);
  float mx = fmaxf(fmaxf(pr0, pr1), fmaxf(pr2, pr3));
  float e0 = expf(pr0 - mx), e1 = expf(pr1 - mx), e2 = expf(pr2 - mx), e3 = expf(pr3 - mx);
  int i1 = 0; float t1 = e0;
  if (e1 > t1) { t1 = e1; i1 = 1; }
  if (e2 > t1) { t1 = e2; i1 = 2; }
  if (e3 > t1) { t1 = e3; i1 = 3; }
  float t2 = -1.f; int i2 = 0;
  if (0 != i1 && e0 > t2) { t2 = e0; i2 = 0; }
  if (1 != i1 && e1 > t2) { t2 = e1; i2 = 1; }
  if (2 != i1 && e2 > t2) { t2 = e2; i2 = 2; }
  if (3 != i1 && e3 > t2) { t2 = e3; i2 = 3; }
  float own = (sub == 0) ? e0 : ((sub == 1) ? e1 : ((sub == 2) ? e2 : e3));
  float gv = (sub == i1 || sub == i2) ? own / (t1 + t2) : 0.f;
  Gout[(size_t)tok * 4 + sub] = gv;
}

// ---------------- MoE token routing ----------------
__global__ void moe_zero_counts(int* counts) {
  if (threadIdx.x < 4) counts[threadIdx.x] = 0;
}
__global__ __launch_bounds__(256) void moe_fill(const float* __restrict__ G,
    int* __restrict__ counts, int* __restrict__ idx, int R)
{
  int tok = blockIdx.x * 256 + threadIdx.x;
  if (tok >= R) return;
  float4 g = *(const float4*)(G + (size_t)tok * 4);
  if (g.x > 0.f) { int p = atomicAdd(counts + 0, 1); idx[0 * Tt + p] = tok; }
  if (g.y > 0.f) { int p = atomicAdd(counts + 1, 1); idx[1 * Tt + p] = tok; }
  if (g.z > 0.f) { int p = atomicAdd(counts + 2, 1); idx[2 * Tt + p] = tok; }
  if (g.w > 0.f) { int p = atomicAdd(counts + 3, 1); idx[3 * Tt + p] = tok; }
}

// ---------------- build xe0 = decomposed concat-proj (dual out) ----------------
__global__ __launch_bounds__(128) void embed_combine(
    const float* __restrict__ xenc, const float* __restrict__ xmark,
    const float* __restrict__ stats, const float* __restrict__ vecs,
    const float* __restrict__ adP, const float* __restrict__ ttP,
    const float* __restrict__ ddP, const float* __restrict__ spP,
    u16* __restrict__ XB, size_t PL)
{
  int t = blockIdx.x;                 // (b*200+n)*96 + l
  int l = t % 96; int bn = t / 96; int n = bn % Nn; int b = bn / Nn;
  float mean = stats[b], rstd = stats[4 + b];
  float x0 = (xenc[((size_t)(b * Ll + l) * Nn + n)] - mean) * rstd;
  float xm = 0.f, xp = 0.f;
  if (l > 0)  xm = (xenc[((size_t)(b * Ll + l - 1) * Nn + n)] - mean) * rstd;
  if (l < 95) xp = (xenc[((size_t)(b * Ll + l + 1) * Nn + n)] - mean) * rstd;
  float trend = (xm + x0 + xp) * (1.f / 3.f);
  float season = x0 - trend;
  const float* mk = xmark + (size_t)(b * Ll + l) * 7;
  float todf = mk[6], dowf = mk[2];
  int ti = (int)(todf * 288.f);
  int di = (int)dowf;
  int j = threadIdx.x;
  float v = trend * vecs[j] + season * vecs[128 + j] + todf * vecs[256 + j] + dowf * vecs[384 + j]
          + vecs[512 + j]
          + adP[((size_t)n * 96 + l) * 128 + j]
          + ttP[(size_t)ti * 128 + j]
          + ddP[(size_t)di * 128 + j]
          + spP[(size_t)bn * 128 + j];
  u16 h = f2b(v);
  XB[(size_t)t * 128 + j] = h;
  XB[PL + (size_t)t * 128 + j] = f2b(v - b2f(h));
}

// ---------------- final RevIN denorm + transpose to [B,PRED,N] ----------------
__global__ void final_out(const float* __restrict__ mixC, const float* __restrict__ mixb,
                          const float* __restrict__ stats, float* __restrict__ out)
{
  int i = blockIdx.x * 256 + threadIdx.x;
  if (i >= Bb * PREDp * Nn) return;
  int n = i % Nn; int p = (i / Nn) % PREDp; int b = i / (Nn * PREDp);
  out[i] = (mixC[((size_t)(b * Nn + n)) * PREDp + p] + mixb[p]) * stats[8 + b] + stats[b];
}

// =======================================================================================
extern "C" void kernel_launch(void* const* d_in, const int* in_sizes, int n_in,
                              void* d_out, int out_size, void* d_ws, size_t ws_size,
                              hipStream_t stream)
{
  const float* x_enc   = (const float*)d_in[0];
  const float* x_mark  = (const float*)d_in[1];
  const float* emb_W   = (const float*)d_in[2];
  const float* emb_b   = (const float*)d_in[3];
  const float* tod_tab = (const float*)d_in[4];
  const float* dow_tab = (const float*)d_in[5];
  const float* adapt   = (const float*)d_in[6];
  const float* sp_W    = (const float*)d_in[7];
  const float* sp_Wq   = (const float*)d_in[8];
  const float* sp_Wk   = (const float*)d_in[9];
  const float* sp_Wv   = (const float*)d_in[10];
  const float* sp_Wo   = (const float*)d_in[11];
  const float* sp_bq   = (const float*)d_in[12];
  const float* sp_bk   = (const float*)d_in[13];
  const float* sp_bv   = (const float*)d_in[14];
  const float* sp_bo   = (const float*)d_in[15];
  const float* sp_proj = (const float*)d_in[16];
  const float* sp_gate = (const float*)d_in[17];
  const float* sp_W1   = (const float*)d_in[18];
  const float* sp_b1   = (const float*)d_in[19];
  const float* sp_W2   = (const float*)d_in[20];
  const float* sp_b2   = (const float*)d_in[21];
  const float* sp_l2g  = (const float*)d_in[22];
  const float* sp_l2b  = (const float*)d_in[23];
  const float* sp_l3g  = (const float*)d_in[24];
  const float* sp_l3b  = (const float*)d_in[25];
  const float* proj_W  = (const float*)d_in[26];
  const float* proj_b  = (const float*)d_in[27];
  const float* LWq     = (const float*)d_in[28];
  const float* LWk     = (const float*)d_in[29];
  const float* LWv     = (const float*)d_in[30];
  const float* LWo     = (const float*)d_in[31];
  const float* Lbq     = (const float*)d_in[32];
  const float* Lbk     = (const float*)d_in[33];
  const float* Lbv     = (const float*)d_in[34];
  const float* Lbo     = (const float*)d_in[35];
  const float* Lproj   = (const float*)d_in[36];
  const float* Lgate   = (const float*)d_in[37];
  const float* LW1     = (const float*)d_in[38];
  const float* Lb1     = (const float*)d_in[39];
  const float* LW2     = (const float*)d_in[40];
  const float* Lb2     = (const float*)d_in[41];
  const float* Ll2g    = (const float*)d_in[42];
  const float* Ll2b    = (const float*)d_in[43];
  const float* Ll3g    = (const float*)d_in[44];
  const float* Ll3b    = (const float*)d_in[45];
  const float* mix_W   = (const float*)d_in[46];
  const float* mix_b   = (const float*)d_in[47];

  if (n_in < 48) return;
  if (in_sizes[0] != Bb * Ll * Nn) return;
  if (in_sizes[26] != 768 * 128) return;
  if (in_sizes[38] != 3 * 4 * 128 * 512) return;
  if (in_sizes[46] != 12288 * 96) return;

  // ---- workspace layout: region A (persistent) + region B (lifetime-overlaid union) ----
  char* base = (char*)d_ws;
  size_t off = 0;
  auto alloc = [&](size_t bytes) -> char* {
    char* p = base + off;
    off += (bytes + 255) & ~(size_t)255;
    return p;
  };
  const size_t PT128 = (size_t)Tt * 128;    // token plane (elems)
  const int CH = Tt / 2;                    // 38400-token chunk for stage-4 attention

  // region A
  float* stats = (float*)alloc(12 * 4);
  float* vecs  = (float*)alloc(5 * 128 * 4);
  float* mixC  = (float*)alloc((size_t)RSEQ * 96 * 4);
  float* Gt    = (float*)alloc((size_t)Tt * 4 * 4);
  float* Gsp   = (float*)alloc((size_t)RSEQ * 4 * 4);
  int* midx    = (int*)alloc((size_t)4 * Tt * 4);
  int* mcnt    = (int*)alloc(256);
  float* qkvb  = (float*)alloc((size_t)3 * 384 * 4);
  u16* XB    = (u16*)alloc(PT128 * 2 * 2);   // dual
  u16* X2B   = (u16*)alloc(PT128 * 2 * 2);   // dual (LN2 out / MoE in)
  float* Rb  = (float*)alloc(PT128 * 4);
  u16* spWt  = (u16*)alloc((size_t)128 * 128 * 2 * 2);
  u16* spWqT = (u16*)alloc((size_t)128 * 128 * 2 * 2);
  u16* spWkT = (u16*)alloc((size_t)128 * 128 * 2 * 2);
  u16* spWvT = (u16*)alloc((size_t)128 * 128 * 2 * 2);
  u16* spWoT = (u16*)alloc((size_t)128 * 128 * 2 * 2);
  u16* LWqkvT = (u16*)alloc((size_t)3 * 384 * 128 * 2 * 2);  // dual
  u16* LWoT  = (u16*)alloc((size_t)3 * 128 * 128 * 2 * 2);
  u16* spW1T = (u16*)alloc((size_t)4 * 512 * 128 * 2 * 2);
  u16* spW2T = (u16*)alloc((size_t)4 * 128 * 512 * 2 * 2);
  u16* LW1T  = (u16*)alloc((size_t)12 * 512 * 128 * 2);      // single-plane
  u16* LW2T  = (u16*)alloc((size_t)12 * 128 * 512 * 2);      // single-plane
  u16* PT    = (u16*)alloc((size_t)4 * 128 * 128 * 2 * 2);
  u16* mixWT = (u16*)alloc((size_t)96 * 12288 * 2 * 2);

  // region B: union of {B1: stage0-3 temps} {B2: fused QKV + AO fp32 per chunk} {B3: MoE Hb}
  const size_t B3 = (size_t)Tt * 512 * 2;                 // 78.64 MB
  char* regB = alloc(B3);
  size_t boff = 0;
  auto balloc = [&](size_t bytes) -> char* {
    char* p = regB + boff;
    boff += (bytes + 255) & ~(size_t)255;
    return p;
  };
  float* adP   = (float*)balloc((size_t)19200 * 128 * 4);
  float* ttP   = (float*)balloc((size_t)288 * 128 * 4);
  float* ddP   = (float*)balloc((size_t)7 * 128 * 4);
  float* spP   = (float*)balloc((size_t)RSEQ * 128 * 4);
  u16* adb     = (u16*)balloc((size_t)19200 * 128 * 2 * 2);
  u16* ttb     = (u16*)balloc((size_t)288 * 128 * 2 * 2);
  u16* ddb     = (u16*)balloc((size_t)7 * 128 * 2 * 2);
  const size_t SPL = (size_t)RSEQ * 128;
  u16* xsb     = (u16*)balloc(SPL * 2 * 2);
  u16* sp0b    = (u16*)balloc(SPL * 2 * 2);
  u16* spaob   = (u16*)balloc(SPL * 2 * 2);
  u16* spx2b   = (u16*)balloc(SPL * 2 * 2);
  u16* spob    = (u16*)balloc(SPL * 2 * 2);
  u16* Hsp     = (u16*)balloc((size_t)RSEQ * 512 * 2 * 2);
  float* spq   = (float*)balloc(SPL * 4);
  float* spk   = (float*)balloc(SPL * 4);
  float* spv   = (float*)balloc(SPL * 4);
  float* spR   = (float*)balloc(SPL * 4);
  // B2: QKVf [CH][384] fp32 (59.0MB) + AOf [CH][128] fp32 (19.66MB) = 78.64MB = B3
  float* QKVf = (float*)regB;
  float* AOf  = QKVf + (size_t)CH * 384;
  // B3
  u16* Hb = (u16*)regB;
  if (off > ws_size || boff > B3) return;  // visible failure (zero output)

  const size_t PL_PT = (size_t)4 * 128 * 128;
  const size_t QKVPL = (size_t)3 * 384 * 128;
  const size_t WOPL  = (size_t)3 * 128 * 128;
  u16* P2T = PT;
  u16* P3T = PT + 128 * 128;
  u16* P4T = PT + 2 * 128 * 128;
  u16* P5T = PT + 3 * 128 * 128;

  auto tp = [&](const float* W, u16* Wt, int K, int N, int KP, int NP, int nb,
                size_t PL, size_t bstride) {
    dim3 g((KP + 31) / 32, (NP + 31) / 32, nb);
    prep_wt_tiled<<<g, dim3(32, 8), 0, stream>>>(W, Wt, K, N, KP, NP, PL, bstride);
  };
  auto gd = [&](const u16* A, size_t aPl, const u16* Bt, size_t bPl, const float* bias,
                float* Cf, u16* Cb, size_t cPl, int R, int K, int N) {
    dim3 g((R + 127) / 128, (N + 127) / 128, 1);
    gemm_bf16<0, 1, 0, 0><<<g, 256, 0, stream>>>(A, aPl, Bt, bPl, bias, Cf, Cb, cPl,
        R, K, N, K, nullptr, 0, 0, nullptr, nullptr);
  };
  auto cpb = [&](const float* s, u16* d, int n, size_t PL) {
    copy_dual<<<(n + 255) / 256, 256, 0, stream>>>(s, d, n, PL);
  };

  // ---- stage 0: stats + weight prep ----
  revin_stats<<<4, 256, 0, stream>>>(x_enc, stats);
  tp(sp_W, spWt, 96, 128, 128, 128, 1, 128 * 128, 128 * 128);
  tp(sp_Wq, spWqT, 128, 128, 128, 128, 1, 128 * 128, 128 * 128);
  tp(sp_Wk, spWkT, 128, 128, 128, 128, 1, 128 * 128, 128 * 128);
  tp(sp_Wv, spWvT, 128, 128, 128, 128, 1, 128 * 128, 128 * 128);
  tp(sp_Wo, spWoT, 128, 128, 128, 128, 1, 128 * 128, 128 * 128);
  tp(LWq, LWqkvT + 0 * 128 * 128, 128, 128, 128, 128, 3, QKVPL, (size_t)384 * 128);
  tp(LWk, LWqkvT + 1 * 128 * 128, 128, 128, 128, 128, 3, QKVPL, (size_t)384 * 128);
  tp(LWv, LWqkvT + 2 * 128 * 128, 128, 128, 128, 128, 3, QKVPL, (size_t)384 * 128);
  tp(LWo, LWoT, 128, 128, 128, 128, 3, WOPL, (size_t)128 * 128);
  tp(sp_W1, spW1T, 128, 512, 128, 512, 4, (size_t)4 * 512 * 128, (size_t)512 * 128);
  tp(sp_W2, spW2T, 512, 128, 512, 128, 4, (size_t)4 * 128 * 512, (size_t)128 * 512);
  tp(LW1, LW1T, 128, 512, 128, 512, 12, 0, (size_t)512 * 128);
  tp(LW2, LW2T, 512, 128, 512, 128, 12, 0, (size_t)128 * 512);
  tp(proj_W + 256 * 128, PT, 128, 128, 128, 128, 4, PL_PT, (size_t)128 * 128);
  tp(mix_W, mixWT, 12288, 96, 12288, 96, 1, (size_t)96 * 12288, (size_t)96 * 12288);
  cpb(adapt, adb, 19200 * 128, (size_t)19200 * 128);
  cpb(tod_tab, ttb, 288 * 128, (size_t)288 * 128);
  cpb(dow_tab, ddb, 7 * 128, (size_t)7 * 128);
  calc_vecs<<<1, 128, 0, stream>>>(emb_W, emb_b, proj_W, proj_b, vecs);
  concat_qkvb<<<(3 * 384 + 127) / 128, 128, 0, stream>>>(Lbq, Lbk, Lbv, qkvb);

  // ---- stage 1: static embedding pieces (dual -> fp32) ----
  gd(adb, (size_t)19200 * 128, P2T, PL_PT, nullptr, adP, nullptr, 0, 19200, 128, 128);
  gd(ttb, (size_t)288 * 128, P3T, PL_PT, nullptr, ttP, nullptr, 0, 288, 128, 128);
  gd(ddb, (size_t)7 * 128, P4T, PL_PT, nullptr, ddP, nullptr, 0, 7, 128, 128);

  // ---- stage 2: spatial transformer block (800 rows, S=1), dual ----
  xs_build<<<RSEQ, 128, 0, stream>>>(x_enc, stats, xsb, SPL);
  gd(xsb, SPL, spWt, 128 * 128, nullptr, nullptr, sp0b, SPL, RSEQ, 128, 128);
  gd(sp0b, SPL, spWqT, 128 * 128, sp_bq, spq, nullptr, 0, RSEQ, 128, 128);
  gd(sp0b, SPL, spWkT, 128 * 128, sp_bk, spk, nullptr, 0, RSEQ, 128, 128);
  gd(sp0b, SPL, spWvT, 128 * 128, sp_bv, spv, nullptr, 0, RSEQ, 128, 128);
  sp_perf<<<RSEQ, 128, 0, stream>>>(spq, spk, spv, sp_proj, spaob, SPL);
  gd(spaob, SPL, spWoT, 128 * 128, sp_bo, spR, nullptr, 0, RSEQ, 128, 128);
  ln_fused<<<RSEQ / 4, 256, 0, stream>>>(sp0b, SPL, spR, sp_l2g, sp_l2b, spx2b, SPL, RSEQ);
  gate_topk<<<(RSEQ * 4 + 255) / 256, 256, 0, stream>>>(spx2b, SPL, sp_gate, Gsp, RSEQ);
  for (int e = 0; e < 4; e++) {
    dim3 g1g((RSEQ + 127) / 128, 4, 1);
    gemm_bf16<1, 1, 0, 0><<<g1g, 256, 0, stream>>>(spx2b, SPL, spW1T + (size_t)e * 512 * 128,
        (size_t)4 * 512 * 128, sp_b1 + e * 512, nullptr, Hsp, (size_t)RSEQ * 512,
        RSEQ, 128, 512, 128, nullptr, 0, 0, nullptr, nullptr);
    dim3 g2g((RSEQ + 127) / 128, 1, 1);
    gemm_bf16<2, 1, 0, 0><<<g2g, 256, 0, stream>>>(Hsp, (size_t)RSEQ * 512,
        spW2T + (size_t)e * 128 * 512, (size_t)4 * 128 * 512, sp_b2 + e * 128, spR, nullptr, 0,
        RSEQ, 512, 128, 512, Gsp, e, e > 0, nullptr, nullptr);
  }
  ln_fused<<<RSEQ / 4, 256, 0, stream>>>(spx2b, SPL, spR, sp_l3g, sp_l3b, spob, SPL, RSEQ);
  gd(spob, SPL, P5T, PL_PT, nullptr, spP, nullptr, 0, RSEQ, 128, 128);

  // ---- stage 3: build xe0 (dual) ----
  embed_combine<<<Tt, 128, 0, stream>>>(x_enc, x_mark, stats, vecs, adP, ttP, ddP, spP, XB, PT128);

  // ---- stage 4: 3 transformer layers ----
  for (int i = 0; i < 3; i++) {
    for (int c = 0; c < 2; c++) {
      const u16* XBc = XB + (size_t)c * CH * 128;      // lo plane at +PT128 relative to XBc
      // fused QKV projection: [CH,128] @ [384,128]^T -> QKVf [CH][384] fp32
      {
        dim3 g((CH + 127) / 128, 3, 1);
        gemm_bf16<0, 1, 0, 0><<<g, 256, 0, stream>>>(XBc, PT128, LWqkvT + (size_t)i * 384 * 128,
            QKVPL, qkvb + i * 384, QKVf, nullptr, 0, CH, 128, 384, 128,
            nullptr, 0, 0, nullptr, nullptr);
      }
      performer_attn2<<<(RSEQ / 2) * 4, 256, 0, stream>>>(QKVf, Lproj + i * 256, AOf);
      // Wo projection: A = AOf fp32 (AF32 split), out Rb chunk
      {
        dim3 g((CH + 127) / 128, 1, 1);
        gemm_bf16<0, 1, 1, 0><<<g, 256, 0, stream>>>((const u16*)AOf, 0,
            LWoT + (size_t)i * 128 * 128, WOPL, Lbo + i * 128, Rb + (size_t)c * CH * 128,
            nullptr, 0, CH, 128, 128, 128, nullptr, 0, 0, nullptr, nullptr);
      }
    }
    ln_fused<<<Tt / 4, 256, 0, stream>>>(XB, PT128, Rb, Ll2g + i * 128, Ll2b + i * 128, X2B, PT128, Tt);
    gate_topk<<<(Tt * 4 + 255) / 256, 256, 0, stream>>>(X2B, PT128, Lgate + i * 512, Gt, Tt);
    moe_zero_counts<<<1, 64, 0, stream>>>(mcnt);
    moe_fill<<<(Tt + 255) / 256, 256, 0, stream>>>(Gt, mcnt, midx, Tt);
    zero_f32<<<(int)((PT128 + 255) / 256), 256, 0, stream>>>(Rb, (int)PT128);
    for (int e = 0; e < 4; e++) {
      int ie = i * 4 + e;
      dim3 g1g((Tt + 127) / 128, 4, 1);
      gemm_bf16<1, 0, 0, 1><<<g1g, 256, 0, stream>>>(X2B, 0, LW1T + (size_t)ie * 512 * 128, 0,
          Lb1 + ie * 512, nullptr, Hb, 0, Tt, 128, 512, 128, nullptr, 0, 0,
          midx + (size_t)e * Tt, mcnt + e);
      // split-K (z=4, kchunk=128) + gate-weighted atomic scatter
      dim3 g2g((Tt + 127) / 128, 1, 4);
      gemm_bf16<2, 0, 0, 2><<<g2g, 256, 0, stream>>>(Hb, 0, LW2T + (size_t)ie * 128 * 512, 0,
          Lb2 + ie * 128, Rb, nullptr, 0, Tt, 512, 128, 128, Gt, e, 1,
          midx + (size_t)e * Tt, mcnt + e);
    }
    ln_fused<<<Tt / 4, 256, 0, stream>>>(X2B, PT128, Rb, Ll3g + i * 128, Ll3b + i * 128, XB, PT128, Tt);
  }

  // ---- stage 5: mix head (dual, split-K atomic) + denorm ----
  zero_f32<<<(RSEQ * 96 + 255) / 256, 256, 0, stream>>>(mixC, RSEQ * 96);
  {
    dim3 g((RSEQ + 127) / 128, 1, 16);  // 16 K-slices of 768
    gemm_bf16<3, 1, 0, 0><<<g, 256, 0, stream>>>(XB, PT128, mixWT, (size_t)96 * 12288, nullptr,
        mixC, nullptr, 0, RSEQ, 12288, 96, 768, nullptr, 0, 0, nullptr, nullptr);
  }
  final_out<<<(Bb * PREDp * Nn + 255) / 256, 256, 0, stream>>>(mixC, mix_b, stats, (float*)d_out);
}

// Round 8
// 2278.475 us; speedup vs baseline: 1.6543x; 1.6543x over previous
//
#include <hip/hip_runtime.h>
#include <stdint.h>

typedef unsigned short u16;
typedef __attribute__((ext_vector_type(8))) __bf16 bf16x8;
typedef __attribute__((ext_vector_type(4))) float f32x4;

// dims
#define Bb 4
#define Ll 96
#define Nn 200
#define Dd 128
#define Hh 8
#define Tt 76800   // B*N*L
#define RSEQ 800   // B*N
#define PREDp 96

__device__ __forceinline__ u16 f2b(float f) {
  union { float f; uint32_t u; } c; c.f = f;
  return (u16)((c.u + 0x7FFFu + ((c.u >> 16) & 1u)) >> 16);
}
__device__ __forceinline__ float b2f(u16 h) {
  union { uint32_t u; float f; } c; c.u = ((uint32_t)h) << 16;
  return c.f;
}

// ============ workhorse GEMM: C[R,N] = A[R,K] @ Bt[N,K]^T ============
// DUAL=1: dual-bf16 planes (hi + lo at +Pl elems); computes Ah*Bh + Ah*Bl + Al*Bh (≈ fp32).
// AF32=1 (requires DUAL=1): A is fp32; hi/lo split happens during LDS staging.
#define LDKV 72

template<int MODE, int DUAL, int AF32>
// MODE: 0 linear, 1 relu, 2 gate-weighted accumulate, 3 atomic split-K
__global__ __launch_bounds__(256) void gemm_bf16(
    const u16* __restrict__ A, size_t aPl, const u16* __restrict__ Bt, size_t bPl,
    const float* __restrict__ bias, float* Cf, u16* Cb, size_t cPl,
    int R, int K, int N, int kchunk,
    const float* __restrict__ G, int expert, int accum)
{
  __shared__ u16 As[128 * LDKV];
  __shared__ u16 Bs[128 * LDKV];
  __shared__ u16 Asl[DUAL ? 128 * LDKV : 2];
  __shared__ u16 Bsl[DUAL ? 128 * LDKV : 2];
  const int tid = threadIdx.x;
  const int bM = blockIdx.x * 128, bN = blockIdx.y * 128;
  const int klo = blockIdx.z * kchunk;
  const int khi = (K < klo + kchunk) ? K : (klo + kchunk);
  const int wave = tid >> 6, lane = tid & 63;
  const int wr = (wave >> 1) * 64, wc = (wave & 1) * 64;
  const int lr = lane & 15, kg = (lane >> 4) * 8;
  f32x4 acc[4][4];
  const f32x4 zz = {0.f, 0.f, 0.f, 0.f};
#pragma unroll
  for (int m = 0; m < 4; m++)
#pragma unroll
    for (int n = 0; n < 4; n++) acc[m][n] = zz;

  for (int k0 = klo; k0 < khi; k0 += 64) {
#pragma unroll
    for (int i = 0; i < 4; i++) {
      int v = tid + i * 256;           // 0..1023 over 128 rows x 8 chunks
      int r = v >> 3, c8 = (v & 7) * 8;
      int gr = bM + r, gc = bN + r;
      bool aok = gr < R;
      if (AF32) {
        const float* Af = (const float*)A;
        float4 f0 = make_float4(0, 0, 0, 0), f1 = make_float4(0, 0, 0, 0);
        if (aok) {
          f0 = *(const float4*)(Af + (size_t)gr * K + k0 + c8);
          f1 = *(const float4*)(Af + (size_t)gr * K + k0 + c8 + 4);
        }
        float ff[8] = {f0.x, f0.y, f0.z, f0.w, f1.x, f1.y, f1.z, f1.w};
        union { int4 v4; u16 us[8]; } hu, lu;
#pragma unroll
        for (int j = 0; j < 8; j++) {
          u16 h = f2b(ff[j]);
          hu.us[j] = h;
          lu.us[j] = f2b(ff[j] - b2f(h));
        }
        *(int4*)(&As[r * LDKV + c8]) = hu.v4;
        *(int4*)(&Asl[r * LDKV + c8]) = lu.v4;
      } else {
        int4 av = make_int4(0, 0, 0, 0);
        if (aok) av = *(const int4*)(A + (size_t)gr * K + k0 + c8);
        *(int4*)(&As[r * LDKV + c8]) = av;
        if (DUAL) {
          int4 av2 = make_int4(0, 0, 0, 0);
          if (aok) av2 = *(const int4*)(A + aPl + (size_t)gr * K + k0 + c8);
          *(int4*)(&Asl[r * LDKV + c8]) = av2;
        }
      }
      int4 bv = make_int4(0, 0, 0, 0);
      if (gc < N) bv = *(const int4*)(Bt + (size_t)gc * K + k0 + c8);
      *(int4*)(&Bs[r * LDKV + c8]) = bv;
      if (DUAL) {
        int4 bv2 = make_int4(0, 0, 0, 0);
        if (gc < N) bv2 = *(const int4*)(Bt + bPl + (size_t)gc * K + k0 + c8);
        *(int4*)(&Bsl[r * LDKV + c8]) = bv2;
      }
    }
    __syncthreads();
#pragma unroll
    for (int kk = 0; kk < 64; kk += 32) {
      bf16x8 ah[4], bh[4], al[4], bl[4];
#pragma unroll
      for (int m = 0; m < 4; m++) ah[m] = *(const bf16x8*)(&As[(wr + m * 16 + lr) * LDKV + kk + kg]);
#pragma unroll
      for (int n = 0; n < 4; n++) bh[n] = *(const bf16x8*)(&Bs[(wc + n * 16 + lr) * LDKV + kk + kg]);
      if (DUAL) {
#pragma unroll
        for (int m = 0; m < 4; m++) al[m] = *(const bf16x8*)(&Asl[(wr + m * 16 + lr) * LDKV + kk + kg]);
#pragma unroll
        for (int n = 0; n < 4; n++) bl[n] = *(const bf16x8*)(&Bsl[(wc + n * 16 + lr) * LDKV + kk + kg]);
      }
#pragma unroll
      for (int m = 0; m < 4; m++)
#pragma unroll
        for (int n = 0; n < 4; n++) {
          acc[m][n] = __builtin_amdgcn_mfma_f32_16x16x32_bf16(ah[m], bh[n], acc[m][n], 0, 0, 0);
          if (DUAL) {
            acc[m][n] = __builtin_amdgcn_mfma_f32_16x16x32_bf16(ah[m], bl[n], acc[m][n], 0, 0, 0);
            acc[m][n] = __builtin_amdgcn_mfma_f32_16x16x32_bf16(al[m], bh[n], acc[m][n], 0, 0, 0);
          }
        }
    }
    __syncthreads();
  }

  const int row0 = bM + wr + (lane >> 4) * 4;
  const int col0 = bN + wc + (lane & 15);
#pragma unroll
  for (int m = 0; m < 4; m++) {
#pragma unroll
    for (int n = 0; n < 4; n++) {
      int col = col0 + n * 16;
      if (col >= N) continue;
#pragma unroll
      for (int r = 0; r < 4; r++) {
        int row = row0 + m * 16 + r;
        if (row >= R) continue;
        float v = acc[m][n][r];
        size_t ci = (size_t)row * N + col;
        if (MODE == 3) {
          atomicAdd(Cf + ci, v);
        } else {
          if (bias) v += bias[col];
          if (MODE == 1) v = fmaxf(v, 0.f);
          if (MODE == 2) {
            v *= G[row * 4 + expert];
            if (accum) v += Cf[ci];
            Cf[ci] = v;
          } else {
            if (Cf) Cf[ci] = v;
            if (Cb) {
              u16 h = f2b(v);
              Cb[ci] = h;
              if (cPl) Cb[cPl + ci] = f2b(v - b2f(h));
            }
          }
        }
      }
    }
  }
}

// ============ fused MoE FFN: per block = 32 gathered tokens x 1 expert ============
// Y[tok_slot] = (relu(X@W1^T + b1) @ W2^T + b2) * gate  — compact non-atomic output Yc.
// H kept in LDS (XOR-swizzled rows); W1/W2 staged per 128x128 chunk (L2-resident).
#define LDH 520
__global__ __launch_bounds__(256) void moe_ffn(
    const u16* __restrict__ X2B, const u16* __restrict__ W1T, const u16* __restrict__ W2T,
    const float* __restrict__ b1, const float* __restrict__ b2,
    const float* __restrict__ G, const int* __restrict__ midx, const int* __restrict__ mcnt,
    const int* __restrict__ js, float* __restrict__ Yc)
{
  __shared__ u16 As[32 * 136];
  __shared__ u16 Ws[128 * 136];
  __shared__ u16 Hs[32 * LDH];
  __shared__ int tok_l[32];
  __shared__ int js_l[32];
  __shared__ float gt_l[32];
  const int e = blockIdx.y;
  const int cnt = mcnt[e];
  const int t0 = blockIdx.x * 32;
  if (t0 >= cnt) return;
  const int tid = threadIdx.x;
  const int wave = tid >> 6, lane = tid & 63;
  const int mw = wave >> 1, nw = wave & 1;
  const int lr = lane & 15, kg = (lane >> 4) * 8;
  const int rowq = (lane >> 4) * 4;
  if (tid < 32) {
    int slot = t0 + tid;
    int tk = (slot < cnt) ? midx[e * Tt + slot] : -1;
    tok_l[tid] = tk;
    js_l[tid] = (slot < cnt) ? js[e * Tt + slot] : 0;
    gt_l[tid] = (tk >= 0) ? G[(size_t)tk * 4 + e] : 0.f;
  }
  __syncthreads();
  // stage A: 32 gathered rows x 128 k (hi plane)
  {
    int v = tid;
#pragma unroll
    for (int i = 0; i < 2; i++, v += 256) {
      int r = v >> 4, c8 = (v & 15) * 8;
      int tk = tok_l[r];
      int4 av = make_int4(0, 0, 0, 0);
      if (tk >= 0) av = *(const int4*)(X2B + (size_t)tk * 128 + c8);
      *(int4*)(&As[r * 136 + c8]) = av;
    }
  }
  const u16* W1e = W1T + (size_t)e * 512 * 128;
  const u16* W2e = W2T + (size_t)e * 128 * 512;
  // GEMM1: H[32][512] = relu(A @ W1e^T + b1), 4 n-subtiles of 128
  for (int ns = 0; ns < 4; ns++) {
    __syncthreads();   // A staged (ns=0) / Ws free (ns>0)
    {
      int v = tid;
#pragma unroll
      for (int i = 0; i < 8; i++, v += 256) {
        int r = v >> 4, c8 = (v & 15) * 8;
        *(int4*)(&Ws[r * 136 + c8]) = *(const int4*)(W1e + (size_t)(ns * 128 + r) * 128 + c8);
      }
    }
    __syncthreads();
    f32x4 acc[4];
    const f32x4 zz = {0.f, 0.f, 0.f, 0.f};
#pragma unroll
    for (int n = 0; n < 4; n++) acc[n] = zz;
#pragma unroll
    for (int kk = 0; kk < 128; kk += 32) {
      bf16x8 a = *(const bf16x8*)(&As[(mw * 16 + lr) * 136 + kk + kg]);
#pragma unroll
      for (int n = 0; n < 4; n++) {
        bf16x8 b = *(const bf16x8*)(&Ws[(nw * 64 + n * 16 + lr) * 136 + kk + kg]);
        acc[n] = __builtin_amdgcn_mfma_f32_16x16x32_bf16(a, b, acc[n], 0, 0, 0);
      }
    }
#pragma unroll
    for (int n = 0; n < 4; n++) {
#pragma unroll
      for (int r = 0; r < 4; r++) {
        int row = mw * 16 + rowq + r;
        int colh = ns * 128 + nw * 64 + n * 16 + lr;
        float hv = fmaxf(acc[n][r] + b1[e * 512 + colh], 0.f);
        Hs[row * LDH + (colh ^ ((row & 7) << 3))] = f2b(hv);
      }
    }
  }
  // GEMM2: out[32][128] = H @ W2e^T, K=512 in 4 chunks
  f32x4 acc2[4];
  const f32x4 zz2 = {0.f, 0.f, 0.f, 0.f};
#pragma unroll
  for (int n = 0; n < 4; n++) acc2[n] = zz2;
  for (int ks = 0; ks < 4; ks++) {
    __syncthreads();   // Hs complete (ks=0) / Ws free
    {
      int v = tid;
#pragma unroll
      for (int i = 0; i < 8; i++, v += 256) {
        int r = v >> 4, c8 = (v & 15) * 8;
        *(int4*)(&Ws[r * 136 + c8]) = *(const int4*)(W2e + (size_t)r * 512 + ks * 128 + c8);
      }
    }
    __syncthreads();
#pragma unroll
    for (int kk = 0; kk < 128; kk += 32) {
      int row = mw * 16 + lr;
      int k = ks * 128 + kk + kg;
      bf16x8 a = *(const bf16x8*)(&Hs[row * LDH + (k ^ ((row & 7) << 3))]);
#pragma unroll
      for (int n = 0; n < 4; n++) {
        bf16x8 b = *(const bf16x8*)(&Ws[(nw * 64 + n * 16 + lr) * 136 + kk + kg]);
        acc2[n] = __builtin_amdgcn_mfma_f32_16x16x32_bf16(a, b, acc2[n], 0, 0, 0);
      }
    }
  }
  // epilogue: compact gate-weighted write, non-atomic
#pragma unroll
  for (int n = 0; n < 4; n++) {
#pragma unroll
    for (int r = 0; r < 4; r++) {
      int rloc = mw * 16 + rowq + r;
      if (t0 + rloc >= cnt) continue;
      int col = nw * 64 + n * 16 + lr;
      float v = (acc2[n][r] + b2[e * 128 + col]) * gt_l[rloc];
      Yc[(size_t)js_l[rloc] * 128 + col] = v;
    }
  }
}

// Rb[t][c] = Yc[2t][c] + Yc[2t+1][c]  (each token has exactly 2 expert slots)
__global__ void moe_combine(const float4* __restrict__ Yc, float4* __restrict__ Rb, int n4) {
  int i = blockIdx.x * 256 + threadIdx.x;
  if (i >= n4) return;
  int t = i >> 5, c = i & 31;
  float4 a = Yc[(size_t)t * 64 + c];
  float4 b = Yc[(size_t)t * 64 + 32 + c];
  float4 o; o.x = a.x + b.x; o.y = a.y + b.y; o.z = a.z + b.z; o.w = a.w + b.w;
  Rb[i] = o;
}

// ---------------- tiled transpose f32 -> dual bf16: Wt[bb][n][k](hi,lo) = W[bb][k][n] ----------------
// PL==0: write hi plane only.
__global__ void prep_wt_tiled(const float* __restrict__ W, u16* __restrict__ Wt,
                              int K, int N, int KP, int NP, size_t PL, size_t bstride)
{
  __shared__ float tile[32][33];
  int k0 = blockIdx.x * 32, n0 = blockIdx.y * 32;
  int bb = blockIdx.z;
  const float* Wb = W + (size_t)bb * K * N;
  u16* Wtb = Wt + (size_t)bb * bstride;
  for (int i = threadIdx.y; i < 32; i += 8) {
    int k = k0 + i, n = n0 + threadIdx.x;
    tile[i][threadIdx.x] = (k < K && n < N) ? Wb[(size_t)k * N + n] : 0.f;
  }
  __syncthreads();
  for (int i = threadIdx.y; i < 32; i += 8) {
    int n = n0 + i, k = k0 + threadIdx.x;
    if (n < NP && k < KP) {
      float v = tile[threadIdx.x][i];
      u16 h = f2b(v);
      Wtb[(size_t)n * KP + k] = h;
      if (PL) Wtb[PL + (size_t)n * KP + k] = f2b(v - b2f(h));
    }
  }
}

__global__ void copy_dual(const float* __restrict__ s, u16* __restrict__ d, int n, size_t PL) {
  int i = blockIdx.x * 256 + threadIdx.x;
  if (i < n) {
    float v = s[i];
    u16 h = f2b(v);
    d[i] = h;
    d[PL + i] = f2b(v - b2f(h));
  }
}
__global__ void zero_f32(float* p, int n) {
  int i = blockIdx.x * 256 + threadIdx.x;
  if (i < n) p[i] = 0.f;
}

// ---------------- RevIN stats per batch ----------------
__global__ __launch_bounds__(256) void revin_stats(const float* __restrict__ x, float* stats) {
  int b = blockIdx.x;
  __shared__ float ss[256], sq[256];
  float s = 0.f, q = 0.f;
  for (int i = threadIdx.x; i < Ll * Nn; i += 256) {
    float v = x[(size_t)b * Ll * Nn + i];
    s += v; q += v * v;
  }
  ss[threadIdx.x] = s; sq[threadIdx.x] = q;
  __syncthreads();
  for (int st = 128; st > 0; st >>= 1) {
    if (threadIdx.x < st) { ss[threadIdx.x] += ss[threadIdx.x + st]; sq[threadIdx.x] += sq[threadIdx.x + st]; }
    __syncthreads();
  }
  if (threadIdx.x == 0) {
    float mean = ss[0] / (float)(Ll * Nn);
    float var = sq[0] / (float)(Ll * Nn) - mean * mean;
    float sd = sqrtf(var + 1e-5f);
    stats[b] = mean; stats[4 + b] = 1.f / sd; stats[8 + b] = sd;
  }
}

// ---------------- combine vectors for the decomposed concat-proj ----------------
__global__ void calc_vecs(const float* __restrict__ embW, const float* __restrict__ embB,
                          const float* __restrict__ projW, const float* __restrict__ projB,
                          float* __restrict__ vecs)
{
  int j = threadIdx.x;  // 128
  float a = 0, b = 0, c = 0, d = 0, e = 0;
  for (int k = 0; k < 128; k++) {
    float p0 = projW[(size_t)k * 128 + j];
    float p1 = projW[(size_t)(128 + k) * 128 + j];
    a += embW[k] * p0;              // trend coeff (emb_W row 0)
    b += embW[k] * p1;              // season coeff
    c += embW[128 + k] * (p0 + p1); // tod coeff (emb_W row 1)
    d += embW[256 + k] * (p0 + p1); // dow coeff (emb_W row 2)
    e += embB[k] * (p0 + p1);
  }
  vecs[j] = a; vecs[128 + j] = b; vecs[256 + j] = c; vecs[384 + j] = d;
  vecs[512 + j] = e + projB[j];
}

// ---------------- concat qkv biases: out[layer][384] ----------------
__global__ void concat_qkvb(const float* __restrict__ bq, const float* __restrict__ bk,
                            const float* __restrict__ bv, float* __restrict__ out)
{
  int t = blockIdx.x * 128 + threadIdx.x;
  if (t >= 3 * 384) return;
  int layer = t / 384, r = t % 384, part = r / 128, col = r % 128;
  const float* src = part == 0 ? bq : (part == 1 ? bk : bv);
  out[t] = src[layer * 128 + col];
}

// ---------------- spatial input: xs[b*N+n][l] = xn (dual), zero-padded to K=128 ----------------
__global__ void xs_build(const float* __restrict__ x, const float* __restrict__ stats,
                         u16* __restrict__ xs, size_t PL)
{
  int r = blockIdx.x;          // b*200+n
  int l = threadIdx.x;         // 128
  int b = r / Nn, n = r % Nn;
  float v = 0.f;
  if (l < Ll) v = (x[((size_t)(b * Ll + l) * Nn + n)] - stats[b]) * stats[4 + b];
  u16 h = f2b(v);
  xs[(size_t)r * 128 + l] = h;
  xs[PL + (size_t)r * 128 + l] = f2b(v - b2f(h));
}

// ---------------- S=1 performer for spatial block: o = v * t/(t+1e-6), fp32 in, dual out ----------------
__global__ __launch_bounds__(128) void sp_perf(const float* __restrict__ qf, const float* __restrict__ kf,
                                               const float* __restrict__ vf, const float* __restrict__ proj,
                                               u16* __restrict__ ob, size_t PL)
{
  int r = blockIdx.x, tid = threadIdx.x;
  __shared__ float ql[128], kl[128], vl[128], ps[256];
  ql[tid] = qf[(size_t)r * 128 + tid] * 0.5f;  // dn = 16^-0.25 = 0.5
  kl[tid] = kf[(size_t)r * 128 + tid] * 0.5f;
  vl[tid] = vf[(size_t)r * 128 + tid];
  ps[tid] = proj[tid]; ps[128 + tid] = proj[128 + tid];
  __syncthreads();
  int h = tid >> 4, m = tid & 15;
  float qd = 0, kd = 0, qn = 0, kn = 0;
#pragma unroll
  for (int d = 0; d < 16; d++) {
    float qv = ql[h * 16 + d], kv_ = kl[h * 16 + d];
    qd += qv * ps[d * 16 + m]; kd += kv_ * ps[d * 16 + m];
    qn += qv * qv; kn += kv_ * kv_;
  }
  qn *= 0.5f; kn *= 0.5f;
  float qmax = qd, kmax = kd;
  for (int msk = 8; msk; msk >>= 1) {
    qmax = fmaxf(qmax, __shfl_xor(qmax, msk, 16));
    kmax = fmaxf(kmax, __shfl_xor(kmax, msk, 16));
  }
  float qp = expf(qd - qn - qmax) * 0.25f + 1e-6f;
  float kp = expf(kd - kn - kmax) * 0.25f + 1e-6f;
  float t = qp * kp;
  for (int msk = 8; msk; msk >>= 1) t += __shfl_xor(t, msk, 16);
  float f = t / (t + 1e-6f);
  float o = vl[tid] * f;
  u16 hh = f2b(o);
  ob[(size_t)r * 128 + tid] = hh;
  ob[PL + (size_t)r * 128 + tid] = f2b(o - b2f(hh));
}

// ---------------- FAVOR+ attention S=96, block = (seq, head-pair), fused qkv input ----------------
__global__ __launch_bounds__(256) void performer_attn2(
    const float* __restrict__ qkv, const float* __restrict__ proj, float* __restrict__ ao)
{
  __shared__ float ks[2][96 * 17];   // k, then kp, then output staging
  __shared__ float vs[2][96 * 17];
  __shared__ float kvs[2][16 * 17];
  __shared__ float ksum[2][16];
  __shared__ float red[2][96];
  __shared__ float ps[256];
  const int tid = threadIdx.x;
  const int seq = blockIdx.x >> 2, hp = blockIdx.x & 3;
  ps[tid] = proj[tid];
#pragma unroll
  for (int i = 0; i < 3; i++) {
    int idx = tid + i * 256;            // 0..767 = 96 rows x 8 slots
    int row = idx >> 3, c4 = idx & 7;
    int hl = c4 >> 2, d0 = (c4 & 3) * 4;
    size_t gb = ((size_t)seq * 96 + row) * 384 + hp * 32 + hl * 16 + d0;
    float4 k4 = *(const float4*)(qkv + gb + 128);
    float4 v4 = *(const float4*)(qkv + gb + 256);
    int lb = row * 17 + d0;
    ks[hl][lb + 0] = k4.x * 0.5f; ks[hl][lb + 1] = k4.y * 0.5f;
    ks[hl][lb + 2] = k4.z * 0.5f; ks[hl][lb + 3] = k4.w * 0.5f;
    vs[hl][lb + 0] = v4.x; vs[hl][lb + 1] = v4.y;
    vs[hl][lb + 2] = v4.z; vs[hl][lb + 3] = v4.w;
  }
  const int h = tid / 96, s = tid - h * 96;   // valid for tid<192
  float q[16];
  if (tid < 192) {
    size_t qb_ = ((size_t)seq * 96 + s) * 384 + hp * 32 + h * 16;
#pragma unroll
    for (int i = 0; i < 4; i++) {
      float4 t = *(const float4*)(qkv + qb_ + i * 4);
      q[i * 4] = t.x * 0.5f; q[i * 4 + 1] = t.y * 0.5f;
      q[i * 4 + 2] = t.z * 0.5f; q[i * 4 + 3] = t.w * 0.5f;
    }
  }
  __syncthreads();
  float qd[16], kd[16], qp[16];
  float qn = 0.f, kn = 0.f;
  if (tid < 192) {
#pragma unroll
    for (int d = 0; d < 16; d++) {
      float kv = ks[h][s * 17 + d];
      qn += q[d] * q[d]; kn += kv * kv;
    }
    qn *= 0.5f; kn *= 0.5f;
#pragma unroll
    for (int m = 0; m < 16; m++) {
      float aq = 0.f, ak = 0.f;
#pragma unroll
      for (int d = 0; d < 16; d++) {
        aq += q[d] * ps[d * 16 + m];
        ak += ks[h][s * 17 + d] * ps[d * 16 + m];
      }
      qd[m] = aq; kd[m] = ak;
    }
    float km = kd[0];
#pragma unroll
    for (int m = 1; m < 16; m++) km = fmaxf(km, kd[m]);
    red[h][s] = km;
  }
  __syncthreads();
  if (tid < 192 && s < 48) red[h][s] = fmaxf(red[h][s], red[h][s + 48]);
  __syncthreads();
  if (tid < 192 && s < 24) red[h][s] = fmaxf(red[h][s], red[h][s + 24]);
  __syncthreads();
  if (tid < 192 && s < 12) red[h][s] = fmaxf(red[h][s], red[h][s + 12]);
  __syncthreads();
  if (tid < 192 && s < 6) red[h][s] = fmaxf(red[h][s], red[h][s + 6]);
  __syncthreads();
  if (tid < 192 && s < 3) red[h][s] = fmaxf(red[h][s], red[h][s + 3]);
  __syncthreads();
  if (tid < 192) {
    float kmax = fmaxf(fmaxf(red[h][0], red[h][1]), red[h][2]);
    float qmx = qd[0];
#pragma unroll
    for (int m = 1; m < 16; m++) qmx = fmaxf(qmx, qd[m]);
#pragma unroll
    for (int m = 0; m < 16; m++) {
      qp[m] = expf(qd[m] - qn - qmx) * 0.25f + 1e-6f;
      ks[h][s * 17 + m] = expf(kd[m] - kn - kmax) * 0.25f + 1e-6f;  // kp overwrites k
    }
  }
  __syncthreads();
#pragma unroll
  for (int it = 0; it < 2; it++) {
    int idx = tid + it * 256;            // 0..511 = (h,m,d)
    int hh = idx >> 8, mm = (idx >> 4) & 15, dd = idx & 15;
    float a0 = 0.f, a1 = 0.f, a2 = 0.f, a3 = 0.f;
    for (int s2 = 0; s2 < 96; s2 += 4) {
      a0 += ks[hh][(s2 + 0) * 17 + mm] * vs[hh][(s2 + 0) * 17 + dd];
      a1 += ks[hh][(s2 + 1) * 17 + mm] * vs[hh][(s2 + 1) * 17 + dd];
      a2 += ks[hh][(s2 + 2) * 17 + mm] * vs[hh][(s2 + 2) * 17 + dd];
      a3 += ks[hh][(s2 + 3) * 17 + mm] * vs[hh][(s2 + 3) * 17 + dd];
    }
    kvs[hh][mm * 17 + dd] = (a0 + a1) + (a2 + a3);
  }
  if (tid < 32) {
    int hh = tid >> 4, mm = tid & 15;
    float a0 = 0.f, a1 = 0.f, a2 = 0.f, a3 = 0.f;
    for (int s2 = 0; s2 < 96; s2 += 4) {
      a0 += ks[hh][(s2 + 0) * 17 + mm];
      a1 += ks[hh][(s2 + 1) * 17 + mm];
      a2 += ks[hh][(s2 + 2) * 17 + mm];
      a3 += ks[hh][(s2 + 3) * 17 + mm];
    }
    ksum[hh][mm] = (a0 + a1) + (a2 + a3);
  }
  __syncthreads();
  if (tid < 192) {
    float zd = 1e-6f;
#pragma unroll
    for (int m = 0; m < 16; m++) zd += qp[m] * ksum[h][m];
    float zi = 1.f / zd;
#pragma unroll
    for (int d = 0; d < 16; d++) {
      float a = 0.f;
#pragma unroll
      for (int m = 0; m < 16; m++) a += qp[m] * kvs[h][m * 17 + d];
      ks[h][s * 17 + d] = a * zi;        // reuse ks as output staging (kp dead)
    }
  }
  __syncthreads();
#pragma unroll
  for (int i = 0; i < 3; i++) {
    int idx = tid + i * 256;
    int row = idx >> 3, c4 = idx & 7;
    int hl = c4 >> 2, d0 = (c4 & 3) * 4;
    int lb = row * 17 + d0;
    float4 o;
    o.x = ks[hl][lb + 0]; o.y = ks[hl][lb + 1]; o.z = ks[hl][lb + 2]; o.w = ks[hl][lb + 3];
    *(float4*)(ao + ((size_t)seq * 96 + row) * 128 + hp * 32 + hl * 16 + d0) = o;
  }
}

// ---------------- fused residual-add + LayerNorm: dual in + f32 res -> dual out ----------------
__global__ __launch_bounds__(256) void ln_fused(const u16* __restrict__ Xin, size_t xPl,
    const float* __restrict__ Res,
    const float* __restrict__ g, const float* __restrict__ bta,
    u16* __restrict__ Out, size_t oPl, int R)
{
  int wave = threadIdx.x >> 6, lane = threadIdx.x & 63;
  int tok = blockIdx.x * 4 + wave;
  if (tok >= R) return;
  size_t bo = (size_t)tok * 128 + lane * 2;
  ushort2 h2 = *(const ushort2*)(Xin + bo);
  ushort2 l2 = *(const ushort2*)(Xin + xPl + bo);
  float2 rv = *(const float2*)(Res + bo);
  float a0 = b2f(h2.x) + b2f(l2.x) + rv.x;
  float a1 = b2f(h2.y) + b2f(l2.y) + rv.y;
  float s = a0 + a1, sq = a0 * a0 + a1 * a1;
  for (int m = 32; m; m >>= 1) { s += __shfl_xor(s, m); sq += __shfl_xor(sq, m); }
  float mean = s * (1.f / 128.f);
  float var = sq * (1.f / 128.f) - mean * mean;
  float rstd = rsqrtf(var + 1e-5f);
  float g0 = g[lane * 2], g1 = g[lane * 2 + 1], b0 = bta[lane * 2], b1 = bta[lane * 2 + 1];
  float o0 = (a0 - mean) * rstd * g0 + b0;
  float o1 = (a1 - mean) * rstd * g1 + b1;
  u16 u0 = f2b(o0), u1 = f2b(o1);
  ushort2 hh; hh.x = u0; hh.y = u1;
  ushort2 ll; ll.x = f2b(o0 - b2f(u0)); ll.y = f2b(o1 - b2f(u1));
  *(ushort2*)(Out + bo) = hh;
  *(ushort2*)(Out + oPl + bo) = ll;
}

// ---------------- MoE gate: softmax top-2 renormalized, dual-bf16 input ----------------
__global__ __launch_bounds__(256) void gate_topk(const u16* __restrict__ X, size_t xPl,
    const float* __restrict__ Wg, float* __restrict__ Gout, int R)
{
  int gid = blockIdx.x * 256 + threadIdx.x;
  int tok = gid >> 2, sub = gid & 3;
  if (tok >= R) return;
  float pr0 = 0, pr1 = 0, pr2 = 0, pr3 = 0;
  for (int d0 = 0; d0 < 32; d0 += 8) {
    size_t idx = (size_t)tok * 128 + sub * 32 + d0;
    int4 hv = *(const int4*)(X + idx);
    int4 lv = *(const int4*)(X + xPl + idx);
    const u16* hp = (const u16*)&hv;
    const u16* lp = (const u16*)&lv;
#pragma unroll
    for (int j = 0; j < 8; j++) {
      float xj = b2f(hp[j]) + b2f(lp[j]);
      float4 w = *(const float4*)(Wg + (size_t)(sub * 32 + d0 + j) * 4);
      pr0 += xj * w.x; pr1 += xj * w.y; pr2 += xj * w.z; pr3 += xj * w.w;
    }
  }
  pr0 += __shfl_xor(pr0, 1, 4); pr0 += __shfl_xor(pr0, 2, 4);
  pr1 += __shfl_xor(pr1, 1, 4); pr1 += __shfl_xor(pr1, 2, 4);
  pr2 += __shfl_xor(pr2, 1, 4); pr2 += __shfl_xor(pr2, 2, 4);
  pr3 += __shfl_xor(pr3, 1, 4); pr3 += __shfl_xor(pr3, 2, 4);
  float mx = fmaxf(fmaxf(pr0, pr1), fmaxf(pr2, pr3));
  float e0 = expf(pr0 - mx), e1 = expf(pr1 - mx), e2 = expf(pr2 - mx), e3 = expf(pr3 - mx);
  int i1 = 0; float t1 = e0;
  if (e1 > t1) { t1 = e1; i1 = 1; }
  if (e2 > t1) { t1 = e2; i1 = 2; }
  if (e3 > t1) { t1 = e3; i1 = 3; }
  float t2 = -1.f; int i2 = 0;
  if (0 != i1 && e0 > t2) { t2 = e0; i2 = 0; }
  if (1 != i1 && e1 > t2) { t2 = e1; i2 = 1; }
  if (2 != i1 && e2 > t2) { t2 = e2; i2 = 2; }
  if (3 != i1 && e3 > t2) { t2 = e3; i2 = 3; }
  float own = (sub == 0) ? e0 : ((sub == 1) ? e1 : ((sub == 2) ? e2 : e3));
  float gv = (sub == i1 || sub == i2) ? own / (t1 + t2) : 0.f;
  Gout[(size_t)tok * 4 + sub] = gv;
}

// ---------------- MoE token routing (records slot -> token*2+j inverse map) ----------------
__global__ void moe_zero_counts(int* counts) {
  if (threadIdx.x < 4) counts[threadIdx.x] = 0;
}
__global__ __launch_bounds__(256) void moe_fill(const float* __restrict__ G,
    int* __restrict__ counts, int* __restrict__ idx, int* __restrict__ js, int R)
{
  int tok = blockIdx.x * 256 + threadIdx.x;
  if (tok >= R) return;
  float4 g = *(const float4*)(G + (size_t)tok * 4);
  int j = 0;
  if (g.x > 0.f) { int p = atomicAdd(counts + 0, 1); idx[0 * Tt + p] = tok; js[0 * Tt + p] = tok * 2 + j; j++; }
  if (g.y > 0.f) { int p = atomicAdd(counts + 1, 1); idx[1 * Tt + p] = tok; js[1 * Tt + p] = tok * 2 + j; j++; }
  if (g.z > 0.f) { int p = atomicAdd(counts + 2, 1); idx[2 * Tt + p] = tok; js[2 * Tt + p] = tok * 2 + j; j++; }
  if (g.w > 0.f) { int p = atomicAdd(counts + 3, 1); idx[3 * Tt + p] = tok; js[3 * Tt + p] = tok * 2 + j; j++; }
}

// ---------------- build xe0 = decomposed concat-proj (dual out) ----------------
__global__ __launch_bounds__(128) void embed_combine(
    const float* __restrict__ xenc, const float* __restrict__ xmark,
    const float* __restrict__ stats, const float* __restrict__ vecs,
    const float* __restrict__ adP, const float* __restrict__ ttP,
    const float* __restrict__ ddP, const float* __restrict__ spP,
    u16* __restrict__ XB, size_t PL)
{
  int t = blockIdx.x;                 // (b*200+n)*96 + l
  int l = t % 96; int bn = t / 96; int n = bn % Nn; int b = bn / Nn;
  float mean = stats[b], rstd = stats[4 + b];
  float x0 = (xenc[((size_t)(b * Ll + l) * Nn + n)] - mean) * rstd;
  float xm = 0.f, xp = 0.f;
  if (l > 0)  xm = (xenc[((size_t)(b * Ll + l - 1) * Nn + n)] - mean) * rstd;
  if (l < 95) xp = (xenc[((size_t)(b * Ll + l + 1) * Nn + n)] - mean) * rstd;
  float trend = (xm + x0 + xp) * (1.f / 3.f);
  float season = x0 - trend;
  const float* mk = xmark + (size_t)(b * Ll + l) * 7;
  float todf = mk[6], dowf = mk[2];
  int ti = (int)(todf * 288.f);
  int di = (int)dowf;
  int j = threadIdx.x;
  float v = trend * vecs[j] + season * vecs[128 + j] + todf * vecs[256 + j] + dowf * vecs[384 + j]
          + vecs[512 + j]
          + adP[((size_t)n * 96 + l) * 128 + j]
          + ttP[(size_t)ti * 128 + j]
          + ddP[(size_t)di * 128 + j]
          + spP[(size_t)bn * 128 + j];
  u16 h = f2b(v);
  XB[(size_t)t * 128 + j] = h;
  XB[PL + (size_t)t * 128 + j] = f2b(v - b2f(h));
}

// ---------------- final RevIN denorm + transpose to [B,PRED,N] ----------------
__global__ void final_out(const float* __restrict__ mixC, const float* __restrict__ mixb,
                          const float* __restrict__ stats, float* __restrict__ out)
{
  int i = blockIdx.x * 256 + threadIdx.x;
  if (i >= Bb * PREDp * Nn) return;
  int n = i % Nn; int p = (i / Nn) % PREDp; int b = i / (Nn * PREDp);
  out[i] = (mixC[((size_t)(b * Nn + n)) * PREDp + p] + mixb[p]) * stats[8 + b] + stats[b];
}

// =======================================================================================
extern "C" void kernel_launch(void* const* d_in, const int* in_sizes, int n_in,
                              void* d_out, int out_size, void* d_ws, size_t ws_size,
                              hipStream_t stream)
{
  const float* x_enc   = (const float*)d_in[0];
  const float* x_mark  = (const float*)d_in[1];
  const float* emb_W   = (const float*)d_in[2];
  const float* emb_b   = (const float*)d_in[3];
  const float* tod_tab = (const float*)d_in[4];
  const float* dow_tab = (const float*)d_in[5];
  const float* adapt   = (const float*)d_in[6];
  const float* sp_W    = (const float*)d_in[7];
  const float* sp_Wq   = (const float*)d_in[8];
  const float* sp_Wk   = (const float*)d_in[9];
  const float* sp_Wv   = (const float*)d_in[10];
  const float* sp_Wo   = (const float*)d_in[11];
  const float* sp_bq   = (const float*)d_in[12];
  const float* sp_bk   = (const float*)d_in[13];
  const float* sp_bv   = (const float*)d_in[14];
  const float* sp_bo   = (const float*)d_in[15];
  const float* sp_proj = (const float*)d_in[16];
  const float* sp_gate = (const float*)d_in[17];
  const float* sp_W1   = (const float*)d_in[18];
  const float* sp_b1   = (const float*)d_in[19];
  const float* sp_W2   = (const float*)d_in[20];
  const float* sp_b2   = (const float*)d_in[21];
  const float* sp_l2g  = (const float*)d_in[22];
  const float* sp_l2b  = (const float*)d_in[23];
  const float* sp_l3g  = (const float*)d_in[24];
  const float* sp_l3b  = (const float*)d_in[25];
  const float* proj_W  = (const float*)d_in[26];
  const float* proj_b  = (const float*)d_in[27];
  const float* LWq     = (const float*)d_in[28];
  const float* LWk     = (const float*)d_in[29];
  const float* LWv     = (const float*)d_in[30];
  const float* LWo     = (const float*)d_in[31];
  const float* Lbq     = (const float*)d_in[32];
  const float* Lbk     = (const float*)d_in[33];
  const float* Lbv     = (const float*)d_in[34];
  const float* Lbo     = (const float*)d_in[35];
  const float* Lproj   = (const float*)d_in[36];
  const float* Lgate   = (const float*)d_in[37];
  const float* LW1     = (const float*)d_in[38];
  const float* Lb1     = (const float*)d_in[39];
  const float* LW2     = (const float*)d_in[40];
  const float* Lb2     = (const float*)d_in[41];
  const float* Ll2g    = (const float*)d_in[42];
  const float* Ll2b    = (const float*)d_in[43];
  const float* Ll3g    = (const float*)d_in[44];
  const float* Ll3b    = (const float*)d_in[45];
  const float* mix_W   = (const float*)d_in[46];
  const float* mix_b   = (const float*)d_in[47];

  if (n_in < 48) return;
  if (in_sizes[0] != Bb * Ll * Nn) return;
  if (in_sizes[26] != 768 * 128) return;
  if (in_sizes[38] != 3 * 4 * 128 * 512) return;
  if (in_sizes[46] != 12288 * 96) return;

  // ---- workspace layout: region A (persistent) + region B (lifetime-overlaid union) ----
  char* base = (char*)d_ws;
  size_t off = 0;
  auto alloc = [&](size_t bytes) -> char* {
    char* p = base + off;
    off += (bytes + 255) & ~(size_t)255;
    return p;
  };
  const size_t PT128 = (size_t)Tt * 128;    // token plane (elems)
  const int CH = Tt / 2;                    // 38400-token chunk for stage-4 attention

  // region A
  float* stats = (float*)alloc(12 * 4);
  float* vecs  = (float*)alloc(5 * 128 * 4);
  float* mixC  = (float*)alloc((size_t)RSEQ * 96 * 4);
  float* Gt    = (float*)alloc((size_t)Tt * 4 * 4);
  float* Gsp   = (float*)alloc((size_t)RSEQ * 4 * 4);
  int* midx    = (int*)alloc((size_t)4 * Tt * 4);
  int* jsarr   = (int*)alloc((size_t)4 * Tt * 4);
  int* mcnt    = (int*)alloc(256);
  float* qkvb  = (float*)alloc((size_t)3 * 384 * 4);
  u16* XB    = (u16*)alloc(PT128 * 2 * 2);   // dual
  u16* X2B   = (u16*)alloc(PT128 * 2 * 2);   // dual (LN2 out / MoE in)
  float* Rb  = (float*)alloc(PT128 * 4);
  u16* spWt  = (u16*)alloc((size_t)128 * 128 * 2 * 2);
  u16* spWqT = (u16*)alloc((size_t)128 * 128 * 2 * 2);
  u16* spWkT = (u16*)alloc((size_t)128 * 128 * 2 * 2);
  u16* spWvT = (u16*)alloc((size_t)128 * 128 * 2 * 2);
  u16* spWoT = (u16*)alloc((size_t)128 * 128 * 2 * 2);
  u16* LWqkvT = (u16*)alloc((size_t)3 * 384 * 128 * 2 * 2);  // dual
  u16* LWoT  = (u16*)alloc((size_t)3 * 128 * 128 * 2 * 2);
  u16* spW1T = (u16*)alloc((size_t)4 * 512 * 128 * 2 * 2);
  u16* spW2T = (u16*)alloc((size_t)4 * 128 * 512 * 2 * 2);
  u16* LW1T  = (u16*)alloc((size_t)12 * 512 * 128 * 2);      // single-plane
  u16* LW2T  = (u16*)alloc((size_t)12 * 128 * 512 * 2);      // single-plane
  u16* PT    = (u16*)alloc((size_t)4 * 128 * 128 * 2 * 2);
  u16* mixWT = (u16*)alloc((size_t)96 * 12288 * 2 * 2);

  // region B: union of {B1: stage0-3 temps} {B2: fused QKV + AO fp32} {B3: MoE compact out Yc}
  const size_t B3 = (size_t)Tt * 2 * 128 * 4;             // Yc: [2*Tt][128] f32 = 78.64 MB
  char* regB = alloc(B3);
  size_t boff = 0;
  auto balloc = [&](size_t bytes) -> char* {
    char* p = regB + boff;
    boff += (bytes + 255) & ~(size_t)255;
    return p;
  };
  float* adP   = (float*)balloc((size_t)19200 * 128 * 4);
  float* ttP   = (float*)balloc((size_t)288 * 128 * 4);
  float* ddP   = (float*)balloc((size_t)7 * 128 * 4);
  float* spP   = (float*)balloc((size_t)RSEQ * 128 * 4);
  u16* adb     = (u16*)balloc((size_t)19200 * 128 * 2 * 2);
  u16* ttb     = (u16*)balloc((size_t)288 * 128 * 2 * 2);
  u16* ddb     = (u16*)balloc((size_t)7 * 128 * 2 * 2);
  const size_t SPL = (size_t)RSEQ * 128;
  u16* xsb     = (u16*)balloc(SPL * 2 * 2);
  u16* sp0b    = (u16*)balloc(SPL * 2 * 2);
  u16* spaob   = (u16*)balloc(SPL * 2 * 2);
  u16* spx2b   = (u16*)balloc(SPL * 2 * 2);
  u16* spob    = (u16*)balloc(SPL * 2 * 2);
  u16* Hsp     = (u16*)balloc((size_t)RSEQ * 512 * 2 * 2);
  float* spq   = (float*)balloc(SPL * 4);
  float* spk   = (float*)balloc(SPL * 4);
  float* spv   = (float*)balloc(SPL * 4);
  float* spR   = (float*)balloc(SPL * 4);
  // B2: QKVf [CH][384] fp32 (59.0MB) + AOf [CH][128] fp32 (19.66MB) = 78.64MB = B3
  float* QKVf = (float*)regB;
  float* AOf  = QKVf + (size_t)CH * 384;
  // B3: MoE compact output
  float* Yc = (float*)regB;
  if (off > ws_size || boff > B3) return;  // visible failure (zero output)

  const size_t PL_PT = (size_t)4 * 128 * 128;
  const size_t QKVPL = (size_t)3 * 384 * 128;
  const size_t WOPL  = (size_t)3 * 128 * 128;
  u16* P2T = PT;
  u16* P3T = PT + 128 * 128;
  u16* P4T = PT + 2 * 128 * 128;
  u16* P5T = PT + 3 * 128 * 128;

  auto tp = [&](const float* W, u16* Wt, int K, int N, int KP, int NP, int nb,
                size_t PL, size_t bstride) {
    dim3 g((KP + 31) / 32, (NP + 31) / 32, nb);
    prep_wt_tiled<<<g, dim3(32, 8), 0, stream>>>(W, Wt, K, N, KP, NP, PL, bstride);
  };
  auto gd = [&](const u16* A, size_t aPl, const u16* Bt, size_t bPl, const float* bias,
                float* Cf, u16* Cb, size_t cPl, int R, int K, int N) {
    dim3 g((R + 127) / 128, (N + 127) / 128, 1);
    gemm_bf16<0, 1, 0><<<g, 256, 0, stream>>>(A, aPl, Bt, bPl, bias, Cf, Cb, cPl,
        R, K, N, K, nullptr, 0, 0);
  };
  auto cpb = [&](const float* s, u16* d, int n, size_t PL) {
    copy_dual<<<(n + 255) / 256, 256, 0, stream>>>(s, d, n, PL);
  };

  // ---- stage 0: stats + weight prep ----
  revin_stats<<<4, 256, 0, stream>>>(x_enc, stats);
  tp(sp_W, spWt, 96, 128, 128, 128, 1, 128 * 128, 128 * 128);
  tp(sp_Wq, spWqT, 128, 128, 128, 128, 1, 128 * 128, 128 * 128);
  tp(sp_Wk, spWkT, 128, 128, 128, 128, 1, 128 * 128, 128 * 128);
  tp(sp_Wv, spWvT, 128, 128, 128, 128, 1, 128 * 128, 128 * 128);
  tp(sp_Wo, spWoT, 128, 128, 128, 128, 1, 128 * 128, 128 * 128);
  tp(LWq, LWqkvT + 0 * 128 * 128, 128, 128, 128, 128, 3, QKVPL, (size_t)384 * 128);
  tp(LWk, LWqkvT + 1 * 128 * 128, 128, 128, 128, 128, 3, QKVPL, (size_t)384 * 128);
  tp(LWv, LWqkvT + 2 * 128 * 128, 128, 128, 128, 128, 3, QKVPL, (size_t)384 * 128);
  tp(LWo, LWoT, 128, 128, 128, 128, 3, WOPL, (size_t)128 * 128);
  tp(sp_W1, spW1T, 128, 512, 128, 512, 4, (size_t)4 * 512 * 128, (size_t)512 * 128);
  tp(sp_W2, spW2T, 512, 128, 512, 128, 4, (size_t)4 * 128 * 512, (size_t)128 * 512);
  tp(LW1, LW1T, 128, 512, 128, 512, 12, 0, (size_t)512 * 128);
  tp(LW2, LW2T, 512, 128, 512, 128, 12, 0, (size_t)128 * 512);
  tp(proj_W + 256 * 128, PT, 128, 128, 128, 128, 4, PL_PT, (size_t)128 * 128);
  tp(mix_W, mixWT, 12288, 96, 12288, 96, 1, (size_t)96 * 12288, (size_t)96 * 12288);
  cpb(adapt, adb, 19200 * 128, (size_t)19200 * 128);
  cpb(tod_tab, ttb, 288 * 128, (size_t)288 * 128);
  cpb(dow_tab, ddb, 7 * 128, (size_t)7 * 128);
  calc_vecs<<<1, 128, 0, stream>>>(emb_W, emb_b, proj_W, proj_b, vecs);
  concat_qkvb<<<(3 * 384 + 127) / 128, 128, 0, stream>>>(Lbq, Lbk, Lbv, qkvb);

  // ---- stage 1: static embedding pieces (dual -> fp32) ----
  gd(adb, (size_t)19200 * 128, P2T, PL_PT, nullptr, adP, nullptr, 0, 19200, 128, 128);
  gd(ttb, (size_t)288 * 128, P3T, PL_PT, nullptr, ttP, nullptr, 0, 288, 128, 128);
  gd(ddb, (size_t)7 * 128, P4T, PL_PT, nullptr, ddP, nullptr, 0, 7, 128, 128);

  // ---- stage 2: spatial transformer block (800 rows, S=1), dual ----
  xs_build<<<RSEQ, 128, 0, stream>>>(x_enc, stats, xsb, SPL);
  gd(xsb, SPL, spWt, 128 * 128, nullptr, nullptr, sp0b, SPL, RSEQ, 128, 128);
  gd(sp0b, SPL, spWqT, 128 * 128, sp_bq, spq, nullptr, 0, RSEQ, 128, 128);
  gd(sp0b, SPL, spWkT, 128 * 128, sp_bk, spk, nullptr, 0, RSEQ, 128, 128);
  gd(sp0b, SPL, spWvT, 128 * 128, sp_bv, spv, nullptr, 0, RSEQ, 128, 128);
  sp_perf<<<RSEQ, 128, 0, stream>>>(spq, spk, spv, sp_proj, spaob, SPL);
  gd(spaob, SPL, spWoT, 128 * 128, sp_bo, spR, nullptr, 0, RSEQ, 128, 128);
  ln_fused<<<RSEQ / 4, 256, 0, stream>>>(sp0b, SPL, spR, sp_l2g, sp_l2b, spx2b, SPL, RSEQ);
  gate_topk<<<(RSEQ * 4 + 255) / 256, 256, 0, stream>>>(spx2b, SPL, sp_gate, Gsp, RSEQ);
  for (int e = 0; e < 4; e++) {
    dim3 g1g((RSEQ + 127) / 128, 4, 1);
    gemm_bf16<1, 1, 0><<<g1g, 256, 0, stream>>>(spx2b, SPL, spW1T + (size_t)e * 512 * 128,
        (size_t)4 * 512 * 128, sp_b1 + e * 512, nullptr, Hsp, (size_t)RSEQ * 512,
        RSEQ, 128, 512, 128, nullptr, 0, 0);
    dim3 g2g((RSEQ + 127) / 128, 1, 1);
    gemm_bf16<2, 1, 0><<<g2g, 256, 0, stream>>>(Hsp, (size_t)RSEQ * 512,
        spW2T + (size_t)e * 128 * 512, (size_t)4 * 128 * 512, sp_b2 + e * 128, spR, nullptr, 0,
        RSEQ, 512, 128, 512, Gsp, e, e > 0);
  }
  ln_fused<<<RSEQ / 4, 256, 0, stream>>>(spx2b, SPL, spR, sp_l3g, sp_l3b, spob, SPL, RSEQ);
  gd(spob, SPL, P5T, PL_PT, nullptr, spP, nullptr, 0, RSEQ, 128, 128);

  // ---- stage 3: build xe0 (dual) ----
  embed_combine<<<Tt, 128, 0, stream>>>(x_enc, x_mark, stats, vecs, adP, ttP, ddP, spP, XB, PT128);

  // ---- stage 4: 3 transformer layers ----
  for (int i = 0; i < 3; i++) {
    for (int c = 0; c < 2; c++) {
      const u16* XBc = XB + (size_t)c * CH * 128;      // lo plane at +PT128 relative to XBc
      {
        dim3 g((CH + 127) / 128, 3, 1);
        gemm_bf16<0, 1, 0><<<g, 256, 0, stream>>>(XBc, PT128, LWqkvT + (size_t)i * 384 * 128,
            QKVPL, qkvb + i * 384, QKVf, nullptr, 0, CH, 128, 384, 128, nullptr, 0, 0);
      }
      performer_attn2<<<(RSEQ / 2) * 4, 256, 0, stream>>>(QKVf, Lproj + i * 256, AOf);
      {
        dim3 g((CH + 127) / 128, 1, 1);
        gemm_bf16<0, 1, 1><<<g, 256, 0, stream>>>((const u16*)AOf, 0,
            LWoT + (size_t)i * 128 * 128, WOPL, Lbo + i * 128, Rb + (size_t)c * CH * 128,
            nullptr, 0, CH, 128, 128, 128, nullptr, 0, 0);
      }
    }
    ln_fused<<<Tt / 4, 256, 0, stream>>>(XB, PT128, Rb, Ll2g + i * 128, Ll2b + i * 128, X2B, PT128, Tt);
    gate_topk<<<(Tt * 4 + 255) / 256, 256, 0, stream>>>(X2B, PT128, Lgate + i * 512, Gt, Tt);
    moe_zero_counts<<<1, 64, 0, stream>>>(mcnt);
    moe_fill<<<(Tt + 255) / 256, 256, 0, stream>>>(Gt, mcnt, midx, jsarr, Tt);
    // fused MoE FFN: one launch covers all 4 experts; compact non-atomic output
    moe_ffn<<<dim3((Tt + 31) / 32, 4), 256, 0, stream>>>(
        X2B, LW1T + (size_t)i * 4 * 512 * 128, LW2T + (size_t)i * 4 * 128 * 512,
        Lb1 + i * 4 * 512, Lb2 + i * 4 * 128, Gt, midx, mcnt, jsarr, Yc);
    moe_combine<<<(Tt * 32 + 255) / 256, 256, 0, stream>>>((const float4*)Yc, (float4*)Rb, Tt * 32);
    ln_fused<<<Tt / 4, 256, 0, stream>>>(X2B, PT128, Rb, Ll3g + i * 128, Ll3b + i * 128, XB, PT128, Tt);
  }

  // ---- stage 5: mix head (dual, split-K atomic) + denorm ----
  zero_f32<<<(RSEQ * 96 + 255) / 256, 256, 0, stream>>>(mixC, RSEQ * 96);
  {
    dim3 g((RSEQ + 127) / 128, 1, 16);  // 16 K-slices of 768
    gemm_bf16<3, 1, 0><<<g, 256, 0, stream>>>(XB, PT128, mixWT, (size_t)96 * 12288, nullptr,
        mixC, nullptr, 0, RSEQ, 12288, 96, 768, nullptr, 0, 0);
  }
  final_out<<<(Bb * PREDp * Nn + 255) / 256, 256, 0, stream>>>(mixC, mix_b, stats, (float*)d_out);
}

// Round 9
// 2177.619 us; speedup vs baseline: 1.7309x; 1.0463x over previous
//
#include <hip/hip_runtime.h>
#include <stdint.h>

typedef unsigned short u16;
typedef __attribute__((ext_vector_type(8))) __bf16 bf16x8;
typedef __attribute__((ext_vector_type(4))) float f32x4;

// dims
#define Bb 4
#define Ll 96
#define Nn 200
#define Dd 128
#define Hh 8
#define Tt 76800   // B*N*L
#define RSEQ 800   // B*N
#define PREDp 96

__device__ __forceinline__ u16 f2b(float f) {
  union { float f; uint32_t u; } c; c.f = f;
  return (u16)((c.u + 0x7FFFu + ((c.u >> 16) & 1u)) >> 16);
}
__device__ __forceinline__ float b2f(u16 h) {
  union { uint32_t u; float f; } c; c.u = ((uint32_t)h) << 16;
  return c.f;
}

// ============ workhorse GEMM: C[R,N] = A[R,K] @ Bt[N,K]^T ============
// DUAL=1: dual-bf16 planes (hi + lo at +Pl elems); computes Ah*Bh + Ah*Bl + Al*Bh (≈ fp32).
// AF32=1 (requires DUAL=1): A is fp32; hi/lo split happens during LDS staging.
#define LDKV 72

template<int MODE, int DUAL, int AF32>
// MODE: 0 linear, 1 relu, 2 gate-weighted accumulate, 3 atomic split-K
__global__ __launch_bounds__(256) void gemm_bf16(
    const u16* __restrict__ A, size_t aPl, const u16* __restrict__ Bt, size_t bPl,
    const float* __restrict__ bias, float* Cf, u16* Cb, size_t cPl,
    int R, int K, int N, int kchunk,
    const float* __restrict__ G, int expert, int accum)
{
  __shared__ u16 As[128 * LDKV];
  __shared__ u16 Bs[128 * LDKV];
  __shared__ u16 Asl[DUAL ? 128 * LDKV : 2];
  __shared__ u16 Bsl[DUAL ? 128 * LDKV : 2];
  const int tid = threadIdx.x;
  const int bM = blockIdx.x * 128, bN = blockIdx.y * 128;
  const int klo = blockIdx.z * kchunk;
  const int khi = (K < klo + kchunk) ? K : (klo + kchunk);
  const int wave = tid >> 6, lane = tid & 63;
  const int wr = (wave >> 1) * 64, wc = (wave & 1) * 64;
  const int lr = lane & 15, kg = (lane >> 4) * 8;
  f32x4 acc[4][4];
  const f32x4 zz = {0.f, 0.f, 0.f, 0.f};
#pragma unroll
  for (int m = 0; m < 4; m++)
#pragma unroll
    for (int n = 0; n < 4; n++) acc[m][n] = zz;

  for (int k0 = klo; k0 < khi; k0 += 64) {
#pragma unroll
    for (int i = 0; i < 4; i++) {
      int v = tid + i * 256;           // 0..1023 over 128 rows x 8 chunks
      int r = v >> 3, c8 = (v & 7) * 8;
      int gr = bM + r, gc = bN + r;
      bool aok = gr < R;
      if (AF32) {
        const float* Af = (const float*)A;
        float4 f0 = make_float4(0, 0, 0, 0), f1 = make_float4(0, 0, 0, 0);
        if (aok) {
          f0 = *(const float4*)(Af + (size_t)gr * K + k0 + c8);
          f1 = *(const float4*)(Af + (size_t)gr * K + k0 + c8 + 4);
        }
        float ff[8] = {f0.x, f0.y, f0.z, f0.w, f1.x, f1.y, f1.z, f1.w};
        union { int4 v4; u16 us[8]; } hu, lu;
#pragma unroll
        for (int j = 0; j < 8; j++) {
          u16 h = f2b(ff[j]);
          hu.us[j] = h;
          lu.us[j] = f2b(ff[j] - b2f(h));
        }
        *(int4*)(&As[r * LDKV + c8]) = hu.v4;
        *(int4*)(&Asl[r * LDKV + c8]) = lu.v4;
      } else {
        int4 av = make_int4(0, 0, 0, 0);
        if (aok) av = *(const int4*)(A + (size_t)gr * K + k0 + c8);
        *(int4*)(&As[r * LDKV + c8]) = av;
        if (DUAL) {
          int4 av2 = make_int4(0, 0, 0, 0);
          if (aok) av2 = *(const int4*)(A + aPl + (size_t)gr * K + k0 + c8);
          *(int4*)(&Asl[r * LDKV + c8]) = av2;
        }
      }
      int4 bv = make_int4(0, 0, 0, 0);
      if (gc < N) bv = *(const int4*)(Bt + (size_t)gc * K + k0 + c8);
      *(int4*)(&Bs[r * LDKV + c8]) = bv;
      if (DUAL) {
        int4 bv2 = make_int4(0, 0, 0, 0);
        if (gc < N) bv2 = *(const int4*)(Bt + bPl + (size_t)gc * K + k0 + c8);
        *(int4*)(&Bsl[r * LDKV + c8]) = bv2;
      }
    }
    __syncthreads();
#pragma unroll
    for (int kk = 0; kk < 64; kk += 32) {
      bf16x8 ah[4], bh[4], al[4], bl[4];
#pragma unroll
      for (int m = 0; m < 4; m++) ah[m] = *(const bf16x8*)(&As[(wr + m * 16 + lr) * LDKV + kk + kg]);
#pragma unroll
      for (int n = 0; n < 4; n++) bh[n] = *(const bf16x8*)(&Bs[(wc + n * 16 + lr) * LDKV + kk + kg]);
      if (DUAL) {
#pragma unroll
        for (int m = 0; m < 4; m++) al[m] = *(const bf16x8*)(&Asl[(wr + m * 16 + lr) * LDKV + kk + kg]);
#pragma unroll
        for (int n = 0; n < 4; n++) bl[n] = *(const bf16x8*)(&Bsl[(wc + n * 16 + lr) * LDKV + kk + kg]);
      }
#pragma unroll
      for (int m = 0; m < 4; m++)
#pragma unroll
        for (int n = 0; n < 4; n++) {
          acc[m][n] = __builtin_amdgcn_mfma_f32_16x16x32_bf16(ah[m], bh[n], acc[m][n], 0, 0, 0);
          if (DUAL) {
            acc[m][n] = __builtin_amdgcn_mfma_f32_16x16x32_bf16(ah[m], bl[n], acc[m][n], 0, 0, 0);
            acc[m][n] = __builtin_amdgcn_mfma_f32_16x16x32_bf16(al[m], bh[n], acc[m][n], 0, 0, 0);
          }
        }
    }
    __syncthreads();
  }

  const int row0 = bM + wr + (lane >> 4) * 4;
  const int col0 = bN + wc + (lane & 15);
#pragma unroll
  for (int m = 0; m < 4; m++) {
#pragma unroll
    for (int n = 0; n < 4; n++) {
      int col = col0 + n * 16;
      if (col >= N) continue;
#pragma unroll
      for (int r = 0; r < 4; r++) {
        int row = row0 + m * 16 + r;
        if (row >= R) continue;
        float v = acc[m][n][r];
        size_t ci = (size_t)row * N + col;
        if (MODE == 3) {
          atomicAdd(Cf + ci, v);
        } else {
          if (bias) v += bias[col];
          if (MODE == 1) v = fmaxf(v, 0.f);
          if (MODE == 2) {
            v *= G[row * 4 + expert];
            if (accum) v += Cf[ci];
            Cf[ci] = v;
          } else {
            if (Cf) Cf[ci] = v;
            if (Cb) {
              u16 h = f2b(v);
              Cb[ci] = h;
              if (cPl) Cb[cPl + ci] = f2b(v - b2f(h));
            }
          }
        }
      }
    }
  }
}

// ============ fused MoE FFN v2: 64 gathered tokens x 1 expert per block ============
// Per 128-wide ns chunk: Hsub = relu(A @ W1ns^T + b1ns) in LDS, then acc2 += Hsub @ W2ns^T.
// No full-H materialization; 136-padded rows -> 2-way (free) LDS banking. Compact output Yc.
#define MT 64
__global__ __launch_bounds__(256) void moe_ffn(
    const u16* __restrict__ X2B, const u16* __restrict__ W1T, const u16* __restrict__ W2T,
    const float* __restrict__ b1, const float* __restrict__ b2,
    const float* __restrict__ G, const int* __restrict__ midx, const int* __restrict__ mcnt,
    const int* __restrict__ js, float* __restrict__ Yc)
{
  __shared__ u16 As[MT * 136];
  __shared__ u16 Ws[128 * 136];
  __shared__ u16 Hs[MT * 136];
  __shared__ int tok_l[MT];
  __shared__ int js_l[MT];
  __shared__ float gt_l[MT];
  const int e = blockIdx.y;
  const int cnt = mcnt[e];
  const int t0 = blockIdx.x * MT;
  if (t0 >= cnt) return;
  const int tid = threadIdx.x;
  const int wave = tid >> 6, lane = tid & 63;
  const int lr = lane & 15, kg = (lane >> 4) * 8;
  const int rowq = (lane >> 4) * 4;
  if (tid < MT) {
    int slot = t0 + tid;
    int tk = (slot < cnt) ? midx[e * Tt + slot] : -1;
    tok_l[tid] = tk;
    js_l[tid] = (slot < cnt) ? js[e * Tt + slot] : 0;
    gt_l[tid] = (tk >= 0) ? G[(size_t)tk * 4 + e] : 0.f;
  }
  __syncthreads();
  // stage A: 64 gathered rows x 128 (single-bf16 hi plane)
  {
    int v = tid;
#pragma unroll
    for (int i = 0; i < 4; i++, v += 256) {
      int r = v >> 4, c8 = (v & 15) * 8;
      int tk = tok_l[r];
      int4 av = make_int4(0, 0, 0, 0);
      if (tk >= 0) av = *(const int4*)(X2B + (size_t)tk * 128 + c8);
      *(int4*)(&As[r * 136 + c8]) = av;
    }
  }
  const u16* W1e = W1T + (size_t)e * 512 * 128;
  const u16* W2e = W2T + (size_t)e * 128 * 512;
  f32x4 acc2[8];
  const f32x4 zz = {0.f, 0.f, 0.f, 0.f};
#pragma unroll
  for (int n = 0; n < 8; n++) acc2[n] = zz;

  for (int ns = 0; ns < 4; ns++) {
    __syncthreads();   // A ready (ns=0) / Ws+Hs free from previous iter
    {
      int v = tid;
#pragma unroll
      for (int i = 0; i < 8; i++, v += 256) {
        int r = v >> 4, c8 = (v & 15) * 8;
        *(int4*)(&Ws[r * 136 + c8]) = *(const int4*)(W1e + (size_t)(ns * 128 + r) * 128 + c8);
      }
    }
    __syncthreads();
    f32x4 acc1[8];
#pragma unroll
    for (int n = 0; n < 8; n++) acc1[n] = zz;
#pragma unroll
    for (int kk = 0; kk < 128; kk += 32) {
      bf16x8 a = *(const bf16x8*)(&As[(wave * 16 + lr) * 136 + kk + kg]);
#pragma unroll
      for (int n = 0; n < 8; n++) {
        bf16x8 b = *(const bf16x8*)(&Ws[(n * 16 + lr) * 136 + kk + kg]);
        acc1[n] = __builtin_amdgcn_mfma_f32_16x16x32_bf16(a, b, acc1[n], 0, 0, 0);
      }
    }
    // Hsub write (wave-private rows): relu + b1
#pragma unroll
    for (int n = 0; n < 8; n++) {
#pragma unroll
      for (int r = 0; r < 4; r++) {
        int row = wave * 16 + rowq + r;
        int col = n * 16 + lr;
        float hv = fmaxf(acc1[n][r] + b1[e * 512 + ns * 128 + col], 0.f);
        Hs[row * 136 + col] = f2b(hv);
      }
    }
    __syncthreads();   // all waves done with Ws (W1ns); Hs visible
    {
      int v = tid;
#pragma unroll
      for (int i = 0; i < 8; i++, v += 256) {
        int r = v >> 4, c8 = (v & 15) * 8;
        *(int4*)(&Ws[r * 136 + c8]) = *(const int4*)(W2e + (size_t)r * 512 + ns * 128 + c8);
      }
    }
    __syncthreads();
#pragma unroll
    for (int kk = 0; kk < 128; kk += 32) {
      bf16x8 a2 = *(const bf16x8*)(&Hs[(wave * 16 + lr) * 136 + kk + kg]);
#pragma unroll
      for (int n = 0; n < 8; n++) {
        bf16x8 b2v = *(const bf16x8*)(&Ws[(n * 16 + lr) * 136 + kk + kg]);
        acc2[n] = __builtin_amdgcn_mfma_f32_16x16x32_bf16(a2, b2v, acc2[n], 0, 0, 0);
      }
    }
  }
  // epilogue: compact gate-weighted write, non-atomic
#pragma unroll
  for (int n = 0; n < 8; n++) {
#pragma unroll
    for (int r = 0; r < 4; r++) {
      int row = wave * 16 + rowq + r;
      if (t0 + row >= cnt) continue;
      int col = n * 16 + lr;
      float v = (acc2[n][r] + b2[e * 128 + col]) * gt_l[row];
      Yc[(size_t)js_l[row] * 128 + col] = v;
    }
  }
}

// ---------------- tiled transpose f32 -> dual bf16: Wt[bb][n][k](hi,lo) = W[bb][k][n] ----------------
// PL==0: write hi plane only.
__global__ void prep_wt_tiled(const float* __restrict__ W, u16* __restrict__ Wt,
                              int K, int N, int KP, int NP, size_t PL, size_t bstride)
{
  __shared__ float tile[32][33];
  int k0 = blockIdx.x * 32, n0 = blockIdx.y * 32;
  int bb = blockIdx.z;
  const float* Wb = W + (size_t)bb * K * N;
  u16* Wtb = Wt + (size_t)bb * bstride;
  for (int i = threadIdx.y; i < 32; i += 8) {
    int k = k0 + i, n = n0 + threadIdx.x;
    tile[i][threadIdx.x] = (k < K && n < N) ? Wb[(size_t)k * N + n] : 0.f;
  }
  __syncthreads();
  for (int i = threadIdx.y; i < 32; i += 8) {
    int n = n0 + i, k = k0 + threadIdx.x;
    if (n < NP && k < KP) {
      float v = tile[threadIdx.x][i];
      u16 h = f2b(v);
      Wtb[(size_t)n * KP + k] = h;
      if (PL) Wtb[PL + (size_t)n * KP + k] = f2b(v - b2f(h));
    }
  }
}

__global__ void copy_dual(const float* __restrict__ s, u16* __restrict__ d, int n, size_t PL) {
  int i = blockIdx.x * 256 + threadIdx.x;
  if (i < n) {
    float v = s[i];
    u16 h = f2b(v);
    d[i] = h;
    d[PL + i] = f2b(v - b2f(h));
  }
}
__global__ void zero_f32(float* p, int n) {
  int i = blockIdx.x * 256 + threadIdx.x;
  if (i < n) p[i] = 0.f;
}

// ---------------- RevIN stats per batch ----------------
__global__ __launch_bounds__(256) void revin_stats(const float* __restrict__ x, float* stats) {
  int b = blockIdx.x;
  __shared__ float ss[256], sq[256];
  float s = 0.f, q = 0.f;
  for (int i = threadIdx.x; i < Ll * Nn; i += 256) {
    float v = x[(size_t)b * Ll * Nn + i];
    s += v; q += v * v;
  }
  ss[threadIdx.x] = s; sq[threadIdx.x] = q;
  __syncthreads();
  for (int st = 128; st > 0; st >>= 1) {
    if (threadIdx.x < st) { ss[threadIdx.x] += ss[threadIdx.x + st]; sq[threadIdx.x] += sq[threadIdx.x + st]; }
    __syncthreads();
  }
  if (threadIdx.x == 0) {
    float mean = ss[0] / (float)(Ll * Nn);
    float var = sq[0] / (float)(Ll * Nn) - mean * mean;
    float sd = sqrtf(var + 1e-5f);
    stats[b] = mean; stats[4 + b] = 1.f / sd; stats[8 + b] = sd;
  }
}

// ---------------- combine vectors for the decomposed concat-proj ----------------
__global__ void calc_vecs(const float* __restrict__ embW, const float* __restrict__ embB,
                          const float* __restrict__ projW, const float* __restrict__ projB,
                          float* __restrict__ vecs)
{
  int j = threadIdx.x;  // 128
  float a = 0, b = 0, c = 0, d = 0, e = 0;
  for (int k = 0; k < 128; k++) {
    float p0 = projW[(size_t)k * 128 + j];
    float p1 = projW[(size_t)(128 + k) * 128 + j];
    a += embW[k] * p0;              // trend coeff (emb_W row 0)
    b += embW[k] * p1;              // season coeff
    c += embW[128 + k] * (p0 + p1); // tod coeff (emb_W row 1)
    d += embW[256 + k] * (p0 + p1); // dow coeff (emb_W row 2)
    e += embB[k] * (p0 + p1);
  }
  vecs[j] = a; vecs[128 + j] = b; vecs[256 + j] = c; vecs[384 + j] = d;
  vecs[512 + j] = e + projB[j];
}

// ---------------- concat qkv biases: out[layer][384] ----------------
__global__ void concat_qkvb(const float* __restrict__ bq, const float* __restrict__ bk,
                            const float* __restrict__ bv, float* __restrict__ out)
{
  int t = blockIdx.x * 128 + threadIdx.x;
  if (t >= 3 * 384) return;
  int layer = t / 384, r = t % 384, part = r / 128, col = r % 128;
  const float* src = part == 0 ? bq : (part == 1 ? bk : bv);
  out[t] = src[layer * 128 + col];
}

// ---------------- spatial input: xs[b*N+n][l] = xn (dual), zero-padded to K=128 ----------------
__global__ void xs_build(const float* __restrict__ x, const float* __restrict__ stats,
                         u16* __restrict__ xs, size_t PL)
{
  int r = blockIdx.x;          // b*200+n
  int l = threadIdx.x;         // 128
  int b = r / Nn, n = r % Nn;
  float v = 0.f;
  if (l < Ll) v = (x[((size_t)(b * Ll + l) * Nn + n)] - stats[b]) * stats[4 + b];
  u16 h = f2b(v);
  xs[(size_t)r * 128 + l] = h;
  xs[PL + (size_t)r * 128 + l] = f2b(v - b2f(h));
}

// ---------------- S=1 performer for spatial block: o = v * t/(t+1e-6), fp32 in, dual out ----------------
__global__ __launch_bounds__(128) void sp_perf(const float* __restrict__ qf, const float* __restrict__ kf,
                                               const float* __restrict__ vf, const float* __restrict__ proj,
                                               u16* __restrict__ ob, size_t PL)
{
  int r = blockIdx.x, tid = threadIdx.x;
  __shared__ float ql[128], kl[128], vl[128], ps[256];
  ql[tid] = qf[(size_t)r * 128 + tid] * 0.5f;  // dn = 16^-0.25 = 0.5
  kl[tid] = kf[(size_t)r * 128 + tid] * 0.5f;
  vl[tid] = vf[(size_t)r * 128 + tid];
  ps[tid] = proj[tid]; ps[128 + tid] = proj[128 + tid];
  __syncthreads();
  int h = tid >> 4, m = tid & 15;
  float qd = 0, kd = 0, qn = 0, kn = 0;
#pragma unroll
  for (int d = 0; d < 16; d++) {
    float qv = ql[h * 16 + d], kv_ = kl[h * 16 + d];
    qd += qv * ps[d * 16 + m]; kd += kv_ * ps[d * 16 + m];
    qn += qv * qv; kn += kv_ * kv_;
  }
  qn *= 0.5f; kn *= 0.5f;
  float qmax = qd, kmax = kd;
  for (int msk = 8; msk; msk >>= 1) {
    qmax = fmaxf(qmax, __shfl_xor(qmax, msk, 16));
    kmax = fmaxf(kmax, __shfl_xor(kmax, msk, 16));
  }
  float qp = expf(qd - qn - qmax) * 0.25f + 1e-6f;
  float kp = expf(kd - kn - kmax) * 0.25f + 1e-6f;
  float t = qp * kp;
  for (int msk = 8; msk; msk >>= 1) t += __shfl_xor(t, msk, 16);
  float f = t / (t + 1e-6f);
  float o = vl[tid] * f;
  u16 hh = f2b(o);
  ob[(size_t)r * 128 + tid] = hh;
  ob[PL + (size_t)r * 128 + tid] = f2b(o - b2f(hh));
}

// ---------------- FAVOR+ attention S=96, block = (seq, head-pair), fused qkv input ----------------
__global__ __launch_bounds__(256) void performer_attn2(
    const float* __restrict__ qkv, const float* __restrict__ proj, float* __restrict__ ao)
{
  __shared__ float ks[2][96 * 17];   // k, then kp, then output staging
  __shared__ float vs[2][96 * 17];
  __shared__ float kvs[2][16 * 17];
  __shared__ float ksum[2][16];
  __shared__ float red[2][96];
  __shared__ float ps[256];
  const int tid = threadIdx.x;
  const int seq = blockIdx.x >> 2, hp = blockIdx.x & 3;
  ps[tid] = proj[tid];
#pragma unroll
  for (int i = 0; i < 3; i++) {
    int idx = tid + i * 256;            // 0..767 = 96 rows x 8 slots
    int row = idx >> 3, c4 = idx & 7;
    int hl = c4 >> 2, d0 = (c4 & 3) * 4;
    size_t gb = ((size_t)seq * 96 + row) * 384 + hp * 32 + hl * 16 + d0;
    float4 k4 = *(const float4*)(qkv + gb + 128);
    float4 v4 = *(const float4*)(qkv + gb + 256);
    int lb = row * 17 + d0;
    ks[hl][lb + 0] = k4.x * 0.5f; ks[hl][lb + 1] = k4.y * 0.5f;
    ks[hl][lb + 2] = k4.z * 0.5f; ks[hl][lb + 3] = k4.w * 0.5f;
    vs[hl][lb + 0] = v4.x; vs[hl][lb + 1] = v4.y;
    vs[hl][lb + 2] = v4.z; vs[hl][lb + 3] = v4.w;
  }
  const int h = tid / 96, s = tid - h * 96;   // valid for tid<192
  float q[16];
  if (tid < 192) {
    size_t qb_ = ((size_t)seq * 96 + s) * 384 + hp * 32 + h * 16;
#pragma unroll
    for (int i = 0; i < 4; i++) {
      float4 t = *(const float4*)(qkv + qb_ + i * 4);
      q[i * 4] = t.x * 0.5f; q[i * 4 + 1] = t.y * 0.5f;
      q[i * 4 + 2] = t.z * 0.5f; q[i * 4 + 3] = t.w * 0.5f;
    }
  }
  __syncthreads();
  float qd[16], kd[16], qp[16];
  float qn = 0.f, kn = 0.f;
  if (tid < 192) {
#pragma unroll
    for (int d = 0; d < 16; d++) {
      float kv = ks[h][s * 17 + d];
      qn += q[d] * q[d]; kn += kv * kv;
    }
    qn *= 0.5f; kn *= 0.5f;
#pragma unroll
    for (int m = 0; m < 16; m++) {
      float aq = 0.f, ak = 0.f;
#pragma unroll
      for (int d = 0; d < 16; d++) {
        aq += q[d] * ps[d * 16 + m];
        ak += ks[h][s * 17 + d] * ps[d * 16 + m];
      }
      qd[m] = aq; kd[m] = ak;
    }
    float km = kd[0];
#pragma unroll
    for (int m = 1; m < 16; m++) km = fmaxf(km, kd[m]);
    red[h][s] = km;
  }
  __syncthreads();
  if (tid < 192 && s < 48) red[h][s] = fmaxf(red[h][s], red[h][s + 48]);
  __syncthreads();
  if (tid < 192 && s < 24) red[h][s] = fmaxf(red[h][s], red[h][s + 24]);
  __syncthreads();
  if (tid < 192 && s < 12) red[h][s] = fmaxf(red[h][s], red[h][s + 12]);
  __syncthreads();
  if (tid < 192 && s < 6) red[h][s] = fmaxf(red[h][s], red[h][s + 6]);
  __syncthreads();
  if (tid < 192 && s < 3) red[h][s] = fmaxf(red[h][s], red[h][s + 3]);
  __syncthreads();
  if (tid < 192) {
    float kmax = fmaxf(fmaxf(red[h][0], red[h][1]), red[h][2]);
    float qmx = qd[0];
#pragma unroll
    for (int m = 1; m < 16; m++) qmx = fmaxf(qmx, qd[m]);
#pragma unroll
    for (int m = 0; m < 16; m++) {
      qp[m] = expf(qd[m] - qn - qmx) * 0.25f + 1e-6f;
      ks[h][s * 17 + m] = expf(kd[m] - kn - kmax) * 0.25f + 1e-6f;  // kp overwrites k
    }
  }
  __syncthreads();
#pragma unroll
  for (int it = 0; it < 2; it++) {
    int idx = tid + it * 256;            // 0..511 = (h,m,d)
    int hh = idx >> 8, mm = (idx >> 4) & 15, dd = idx & 15;
    float a0 = 0.f, a1 = 0.f, a2 = 0.f, a3 = 0.f;
    for (int s2 = 0; s2 < 96; s2 += 4) {
      a0 += ks[hh][(s2 + 0) * 17 + mm] * vs[hh][(s2 + 0) * 17 + dd];
      a1 += ks[hh][(s2 + 1) * 17 + mm] * vs[hh][(s2 + 1) * 17 + dd];
      a2 += ks[hh][(s2 + 2) * 17 + mm] * vs[hh][(s2 + 2) * 17 + dd];
      a3 += ks[hh][(s2 + 3) * 17 + mm] * vs[hh][(s2 + 3) * 17 + dd];
    }
    kvs[hh][mm * 17 + dd] = (a0 + a1) + (a2 + a3);
  }
  if (tid < 32) {
    int hh = tid >> 4, mm = tid & 15;
    float a0 = 0.f, a1 = 0.f, a2 = 0.f, a3 = 0.f;
    for (int s2 = 0; s2 < 96; s2 += 4) {
      a0 += ks[hh][(s2 + 0) * 17 + mm];
      a1 += ks[hh][(s2 + 1) * 17 + mm];
      a2 += ks[hh][(s2 + 2) * 17 + mm];
      a3 += ks[hh][(s2 + 3) * 17 + mm];
    }
    ksum[hh][mm] = (a0 + a1) + (a2 + a3);
  }
  __syncthreads();
  if (tid < 192) {
    float zd = 1e-6f;
#pragma unroll
    for (int m = 0; m < 16; m++) zd += qp[m] * ksum[h][m];
    float zi = 1.f / zd;
#pragma unroll
    for (int d = 0; d < 16; d++) {
      float a = 0.f;
#pragma unroll
      for (int m = 0; m < 16; m++) a += qp[m] * kvs[h][m * 17 + d];
      ks[h][s * 17 + d] = a * zi;        // reuse ks as output staging (kp dead)
    }
  }
  __syncthreads();
#pragma unroll
  for (int i = 0; i < 3; i++) {
    int idx = tid + i * 256;
    int row = idx >> 3, c4 = idx & 7;
    int hl = c4 >> 2, d0 = (c4 & 3) * 4;
    int lb = row * 17 + d0;
    float4 o;
    o.x = ks[hl][lb + 0]; o.y = ks[hl][lb + 1]; o.z = ks[hl][lb + 2]; o.w = ks[hl][lb + 3];
    *(float4*)(ao + ((size_t)seq * 96 + row) * 128 + hp * 32 + hl * 16 + d0) = o;
  }
}

// ---------------- fused residual-add + LayerNorm: dual in + 1or2 f32 residuals -> dual out ----------------
__global__ __launch_bounds__(256) void ln_fused(const u16* __restrict__ Xin, size_t xPl,
    const float* __restrict__ Res, int rStride, const float* __restrict__ Res2,
    const float* __restrict__ g, const float* __restrict__ bta,
    u16* __restrict__ Out, size_t oPl, int R)
{
  int wave = threadIdx.x >> 6, lane = threadIdx.x & 63;
  int tok = blockIdx.x * 4 + wave;
  if (tok >= R) return;
  size_t bo = (size_t)tok * 128 + lane * 2;
  size_t ro = (size_t)tok * rStride + lane * 2;
  ushort2 h2 = *(const ushort2*)(Xin + bo);
  ushort2 l2 = *(const ushort2*)(Xin + xPl + bo);
  float2 rv = *(const float2*)(Res + ro);
  float a0 = b2f(h2.x) + b2f(l2.x) + rv.x;
  float a1 = b2f(h2.y) + b2f(l2.y) + rv.y;
  if (Res2) {
    float2 r2 = *(const float2*)(Res2 + ro);
    a0 += r2.x; a1 += r2.y;
  }
  float s = a0 + a1, sq = a0 * a0 + a1 * a1;
  for (int m = 32; m; m >>= 1) { s += __shfl_xor(s, m); sq += __shfl_xor(sq, m); }
  float mean = s * (1.f / 128.f);
  float var = sq * (1.f / 128.f) - mean * mean;
  float rstd = rsqrtf(var + 1e-5f);
  float g0 = g[lane * 2], g1 = g[lane * 2 + 1], b0 = bta[lane * 2], b1 = bta[lane * 2 + 1];
  float o0 = (a0 - mean) * rstd * g0 + b0;
  float o1 = (a1 - mean) * rstd * g1 + b1;
  u16 u0 = f2b(o0), u1 = f2b(o1);
  ushort2 hh; hh.x = u0; hh.y = u1;
  ushort2 ll; ll.x = f2b(o0 - b2f(u0)); ll.y = f2b(o1 - b2f(u1));
  *(ushort2*)(Out + bo) = hh;
  *(ushort2*)(Out + oPl + bo) = ll;
}

// ---------------- MoE gate: softmax top-2 renormalized, dual-bf16 input ----------------
__global__ __launch_bounds__(256) void gate_topk(const u16* __restrict__ X, size_t xPl,
    const float* __restrict__ Wg, float* __restrict__ Gout, int R)
{
  int gid = blockIdx.x * 256 + threadIdx.x;
  int tok = gid >> 2, sub = gid & 3;
  if (tok >= R) return;
  float pr0 = 0, pr1 = 0, pr2 = 0, pr3 = 0;
  for (int d0 = 0; d0 < 32; d0 += 8) {
    size_t idx = (size_t)tok * 128 + sub * 32 + d0;
    int4 hv = *(const int4*)(X + idx);
    int4 lv = *(const int4*)(X + xPl + idx);
    const u16* hp = (const u16*)&hv;
    const u16* lp = (const u16*)&lv;
#pragma unroll
    for (int j = 0; j < 8; j++) {
      float xj = b2f(hp[j]) + b2f(lp[j]);
      float4 w = *(const float4*)(Wg + (size_t)(sub * 32 + d0 + j) * 4);
      pr0 += xj * w.x; pr1 += xj * w.y; pr2 += xj * w.z; pr3 += xj * w.w;
    }
  }
  pr0 += __shfl_xor(pr0, 1, 4); pr0 += __shfl_xor(pr0, 2, 4);
  pr1 += __shfl_xor(pr1, 1, 4); pr1 += __shfl_xor(pr1, 2, 4);
  pr2 += __shfl_xor(pr2, 1, 4); pr2 += __shfl_xor(pr2, 2, 4);
  pr3 += __shfl_xor(pr3, 1, 4); pr3 += __shfl_xor(pr3, 2, 4);
  float mx = fmaxf(fmaxf(pr0, pr1), fmaxf(pr2, pr3));
  float e0 = expf(pr0 - mx), e1 = expf(pr1 - mx), e2 = expf(pr2 - mx), e3 = expf(pr3 - mx);
  int i1 = 0; float t1 = e0;
  if (e1 > t1) { t1 = e1; i1 = 1; }
  if (e2 > t1) { t1 = e2; i1 = 2; }
  if (e3 > t1) { t1 = e3; i1 = 3; }
  float t2 = -1.f; int i2 = 0;
  if (0 != i1 && e0 > t2) { t2 = e0; i2 = 0; }
  if (1 != i1 && e1 > t2) { t2 = e1; i2 = 1; }
  if (2 != i1 && e2 > t2) { t2 = e2; i2 = 2; }
  if (3 != i1 && e3 > t2) { t2 = e3; i2 = 3; }
  float own = (sub == 0) ? e0 : ((sub == 1) ? e1 : ((sub == 2) ? e2 : e3));
  float gv = (sub == i1 || sub == i2) ? own / (t1 + t2) : 0.f;
  Gout[(size_t)tok * 4 + sub] = gv;
}

// ---------------- MoE token routing (records slot -> token*2+j inverse map) ----------------
__global__ void moe_zero_counts(int* counts) {
  if (threadIdx.x < 4) counts[threadIdx.x] = 0;
}
__global__ __launch_bounds__(256) void moe_fill(const float* __restrict__ G,
    int* __restrict__ counts, int* __restrict__ idx, int* __restrict__ js, int R)
{
  int tok = blockIdx.x * 256 + threadIdx.x;
  if (tok >= R) return;
  float4 g = *(const float4*)(G + (size_t)tok * 4);
  int j = 0;
  if (g.x > 0.f) { int p = atomicAdd(counts + 0, 1); idx[0 * Tt + p] = tok; js[0 * Tt + p] = tok * 2 + j; j++; }
  if (g.y > 0.f) { int p = atomicAdd(counts + 1, 1); idx[1 * Tt + p] = tok; js[1 * Tt + p] = tok * 2 + j; j++; }
  if (g.z > 0.f) { int p = atomicAdd(counts + 2, 1); idx[2 * Tt + p] = tok; js[2 * Tt + p] = tok * 2 + j; j++; }
  if (g.w > 0.f) { int p = atomicAdd(counts + 3, 1); idx[3 * Tt + p] = tok; js[3 * Tt + p] = tok * 2 + j; j++; }
}

// ---------------- build xe0 = decomposed concat-proj (dual out) ----------------
__global__ __launch_bounds__(128) void embed_combine(
    const float* __restrict__ xenc, const float* __restrict__ xmark,
    const float* __restrict__ stats, const float* __restrict__ vecs,
    const float* __restrict__ adP, const float* __restrict__ ttP,
    const float* __restrict__ ddP, const float* __restrict__ spP,
    u16* __restrict__ XB, size_t PL)
{
  int t = blockIdx.x;                 // (b*200+n)*96 + l
  int l = t % 96; int bn = t / 96; int n = bn % Nn; int b = bn / Nn;
  float mean = stats[b], rstd = stats[4 + b];
  float x0 = (xenc[((size_t)(b * Ll + l) * Nn + n)] - mean) * rstd;
  float xm = 0.f, xp = 0.f;
  if (l > 0)  xm = (xenc[((size_t)(b * Ll + l - 1) * Nn + n)] - mean) * rstd;
  if (l < 95) xp = (xenc[((size_t)(b * Ll + l + 1) * Nn + n)] - mean) * rstd;
  float trend = (xm + x0 + xp) * (1.f / 3.f);
  float season = x0 - trend;
  const float* mk = xmark + (size_t)(b * Ll + l) * 7;
  float todf = mk[6], dowf = mk[2];
  int ti = (int)(todf * 288.f);
  int di = (int)dowf;
  int j = threadIdx.x;
  float v = trend * vecs[j] + season * vecs[128 + j] + todf * vecs[256 + j] + dowf * vecs[384 + j]
          + vecs[512 + j]
          + adP[((size_t)n * 96 + l) * 128 + j]
          + ttP[(size_t)ti * 128 + j]
          + ddP[(size_t)di * 128 + j]
          + spP[(size_t)bn * 128 + j];
  u16 h = f2b(v);
  XB[(size_t)t * 128 + j] = h;
  XB[PL + (size_t)t * 128 + j] = f2b(v - b2f(h));
}

// ---------------- final RevIN denorm + transpose to [B,PRED,N] ----------------
__global__ void final_out(const float* __restrict__ mixC, const float* __restrict__ mixb,
                          const float* __restrict__ stats, float* __restrict__ out)
{
  int i = blockIdx.x * 256 + threadIdx.x;
  if (i >= Bb * PREDp * Nn) return;
  int n = i % Nn; int p = (i / Nn) % PREDp; int b = i / (Nn * PREDp);
  out[i] = (mixC[((size_t)(b * Nn + n)) * PREDp + p] + mixb[p]) * stats[8 + b] + stats[b];
}

// =======================================================================================
extern "C" void kernel_launch(void* const* d_in, const int* in_sizes, int n_in,
                              void* d_out, int out_size, void* d_ws, size_t ws_size,
                              hipStream_t stream)
{
  const float* x_enc   = (const float*)d_in[0];
  const float* x_mark  = (const float*)d_in[1];
  const float* emb_W   = (const float*)d_in[2];
  const float* emb_b   = (const float*)d_in[3];
  const float* tod_tab = (const float*)d_in[4];
  const float* dow_tab = (const float*)d_in[5];
  const float* adapt   = (const float*)d_in[6];
  const float* sp_W    = (const float*)d_in[7];
  const float* sp_Wq   = (const float*)d_in[8];
  const float* sp_Wk   = (const float*)d_in[9];
  const float* sp_Wv   = (const float*)d_in[10];
  const float* sp_Wo   = (const float*)d_in[11];
  const float* sp_bq   = (const float*)d_in[12];
  const float* sp_bk   = (const float*)d_in[13];
  const float* sp_bv   = (const float*)d_in[14];
  const float* sp_bo   = (const float*)d_in[15];
  const float* sp_proj = (const float*)d_in[16];
  const float* sp_gate = (const float*)d_in[17];
  const float* sp_W1   = (const float*)d_in[18];
  const float* sp_b1   = (const float*)d_in[19];
  const float* sp_W2   = (const float*)d_in[20];
  const float* sp_b2   = (const float*)d_in[21];
  const float* sp_l2g  = (const float*)d_in[22];
  const float* sp_l2b  = (const float*)d_in[23];
  const float* sp_l3g  = (const float*)d_in[24];
  const float* sp_l3b  = (const float*)d_in[25];
  const float* proj_W  = (const float*)d_in[26];
  const float* proj_b  = (const float*)d_in[27];
  const float* LWq     = (const float*)d_in[28];
  const float* LWk     = (const float*)d_in[29];
  const float* LWv     = (const float*)d_in[30];
  const float* LWo     = (const float*)d_in[31];
  const float* Lbq     = (const float*)d_in[32];
  const float* Lbk     = (const float*)d_in[33];
  const float* Lbv     = (const float*)d_in[34];
  const float* Lbo     = (const float*)d_in[35];
  const float* Lproj   = (const float*)d_in[36];
  const float* Lgate   = (const float*)d_in[37];
  const float* LW1     = (const float*)d_in[38];
  const float* Lb1     = (const float*)d_in[39];
  const float* LW2     = (const float*)d_in[40];
  const float* Lb2     = (const float*)d_in[41];
  const float* Ll2g    = (const float*)d_in[42];
  const float* Ll2b    = (const float*)d_in[43];
  const float* Ll3g    = (const float*)d_in[44];
  const float* Ll3b    = (const float*)d_in[45];
  const float* mix_W   = (const float*)d_in[46];
  const float* mix_b   = (const float*)d_in[47];

  if (n_in < 48) return;
  if (in_sizes[0] != Bb * Ll * Nn) return;
  if (in_sizes[26] != 768 * 128) return;
  if (in_sizes[38] != 3 * 4 * 128 * 512) return;
  if (in_sizes[46] != 12288 * 96) return;

  // ---- workspace layout: region A (persistent) + region B (lifetime-overlaid union) ----
  char* base = (char*)d_ws;
  size_t off = 0;
  auto alloc = [&](size_t bytes) -> char* {
    char* p = base + off;
    off += (bytes + 255) & ~(size_t)255;
    return p;
  };
  const size_t PT128 = (size_t)Tt * 128;    // token plane (elems)
  const int CH = Tt / 2;                    // 38400-token chunk for stage-4 attention

  // region A
  float* stats = (float*)alloc(12 * 4);
  float* vecs  = (float*)alloc(5 * 128 * 4);
  float* mixC  = (float*)alloc((size_t)RSEQ * 96 * 4);
  float* Gt    = (float*)alloc((size_t)Tt * 4 * 4);
  float* Gsp   = (float*)alloc((size_t)RSEQ * 4 * 4);
  int* midx    = (int*)alloc((size_t)4 * Tt * 4);
  int* jsarr   = (int*)alloc((size_t)4 * Tt * 4);
  int* mcnt    = (int*)alloc(256);
  float* qkvb  = (float*)alloc((size_t)3 * 384 * 4);
  u16* XB    = (u16*)alloc(PT128 * 2 * 2);   // dual
  u16* X2B   = (u16*)alloc(PT128 * 2 * 2);   // dual (LN2 out / MoE in)
  float* Rb  = (float*)alloc(PT128 * 4);
  u16* spWt  = (u16*)alloc((size_t)128 * 128 * 2 * 2);
  u16* spWqT = (u16*)alloc((size_t)128 * 128 * 2 * 2);
  u16* spWkT = (u16*)alloc((size_t)128 * 128 * 2 * 2);
  u16* spWvT = (u16*)alloc((size_t)128 * 128 * 2 * 2);
  u16* spWoT = (u16*)alloc((size_t)128 * 128 * 2 * 2);
  u16* LWqkvT = (u16*)alloc((size_t)3 * 384 * 128 * 2 * 2);  // dual
  u16* LWoT  = (u16*)alloc((size_t)3 * 128 * 128 * 2 * 2);
  u16* spW1T = (u16*)alloc((size_t)4 * 512 * 128 * 2 * 2);
  u16* spW2T = (u16*)alloc((size_t)4 * 128 * 512 * 2 * 2);
  u16* LW1T  = (u16*)alloc((size_t)12 * 512 * 128 * 2);      // single-plane
  u16* LW2T  = (u16*)alloc((size_t)12 * 128 * 512 * 2);      // single-plane
  u16* PT    = (u16*)alloc((size_t)4 * 128 * 128 * 2 * 2);
  u16* mixWT = (u16*)alloc((size_t)96 * 12288 * 2 * 2);

  // region B: union of {B1: stage0-3 temps} {B2: fused QKV + AO fp32} {B3: MoE compact out Yc}
  const size_t B3 = (size_t)Tt * 2 * 128 * 4;             // Yc: [2*Tt][128] f32 = 78.64 MB
  char* regB = alloc(B3);
  size_t boff = 0;
  auto balloc = [&](size_t bytes) -> char* {
    char* p = regB + boff;
    boff += (bytes + 255) & ~(size_t)255;
    return p;
  };
  float* adP   = (float*)balloc((size_t)19200 * 128 * 4);
  float* ttP   = (float*)balloc((size_t)288 * 128 * 4);
  float* ddP   = (float*)balloc((size_t)7 * 128 * 4);
  float* spP   = (float*)balloc((size_t)RSEQ * 128 * 4);
  u16* adb     = (u16*)balloc((size_t)19200 * 128 * 2 * 2);
  u16* ttb     = (u16*)balloc((size_t)288 * 128 * 2 * 2);
  u16* ddb     = (u16*)balloc((size_t)7 * 128 * 2 * 2);
  const size_t SPL = (size_t)RSEQ * 128;
  u16* xsb     = (u16*)balloc(SPL * 2 * 2);
  u16* sp0b    = (u16*)balloc(SPL * 2 * 2);
  u16* spaob   = (u16*)balloc(SPL * 2 * 2);
  u16* spx2b   = (u16*)balloc(SPL * 2 * 2);
  u16* spob    = (u16*)balloc(SPL * 2 * 2);
  u16* Hsp     = (u16*)balloc((size_t)RSEQ * 512 * 2 * 2);
  float* spq   = (float*)balloc(SPL * 4);
  float* spk   = (float*)balloc(SPL * 4);
  float* spv   = (float*)balloc(SPL * 4);
  float* spR   = (float*)balloc(SPL * 4);
  // B2: QKVf [CH][384] fp32 (59.0MB) + AOf [CH][128] fp32 (19.66MB) = 78.64MB = B3
  float* QKVf = (float*)regB;
  float* AOf  = QKVf + (size_t)CH * 384;
  // B3: MoE compact output
  float* Yc = (float*)regB;
  if (off > ws_size || boff > B3) return;  // visible failure (zero output)

  const size_t PL_PT = (size_t)4 * 128 * 128;
  const size_t QKVPL = (size_t)3 * 384 * 128;
  const size_t WOPL  = (size_t)3 * 128 * 128;
  u16* P2T = PT;
  u16* P3T = PT + 128 * 128;
  u16* P4T = PT + 2 * 128 * 128;
  u16* P5T = PT + 3 * 128 * 128;

  auto tp = [&](const float* W, u16* Wt, int K, int N, int KP, int NP, int nb,
                size_t PL, size_t bstride) {
    dim3 g((KP + 31) / 32, (NP + 31) / 32, nb);
    prep_wt_tiled<<<g, dim3(32, 8), 0, stream>>>(W, Wt, K, N, KP, NP, PL, bstride);
  };
  auto gd = [&](const u16* A, size_t aPl, const u16* Bt, size_t bPl, const float* bias,
                float* Cf, u16* Cb, size_t cPl, int R, int K, int N) {
    dim3 g((R + 127) / 128, (N + 127) / 128, 1);
    gemm_bf16<0, 1, 0><<<g, 256, 0, stream>>>(A, aPl, Bt, bPl, bias, Cf, Cb, cPl,
        R, K, N, K, nullptr, 0, 0);
  };
  auto cpb = [&](const float* s, u16* d, int n, size_t PL) {
    copy_dual<<<(n + 255) / 256, 256, 0, stream>>>(s, d, n, PL);
  };

  // ---- stage 0: stats + weight prep ----
  revin_stats<<<4, 256, 0, stream>>>(x_enc, stats);
  tp(sp_W, spWt, 96, 128, 128, 128, 1, 128 * 128, 128 * 128);
  tp(sp_Wq, spWqT, 128, 128, 128, 128, 1, 128 * 128, 128 * 128);
  tp(sp_Wk, spWkT, 128, 128, 128, 128, 1, 128 * 128, 128 * 128);
  tp(sp_Wv, spWvT, 128, 128, 128, 128, 1, 128 * 128, 128 * 128);
  tp(sp_Wo, spWoT, 128, 128, 128, 128, 1, 128 * 128, 128 * 128);
  tp(LWq, LWqkvT + 0 * 128 * 128, 128, 128, 128, 128, 3, QKVPL, (size_t)384 * 128);
  tp(LWk, LWqkvT + 1 * 128 * 128, 128, 128, 128, 128, 3, QKVPL, (size_t)384 * 128);
  tp(LWv, LWqkvT + 2 * 128 * 128, 128, 128, 128, 128, 3, QKVPL, (size_t)384 * 128);
  tp(LWo, LWoT, 128, 128, 128, 128, 3, WOPL, (size_t)128 * 128);
  tp(sp_W1, spW1T, 128, 512, 128, 512, 4, (size_t)4 * 512 * 128, (size_t)512 * 128);
  tp(sp_W2, spW2T, 512, 128, 512, 128, 4, (size_t)4 * 128 * 512, (size_t)128 * 512);
  tp(LW1, LW1T, 128, 512, 128, 512, 12, 0, (size_t)512 * 128);
  tp(LW2, LW2T, 512, 128, 512, 128, 12, 0, (size_t)128 * 512);
  tp(proj_W + 256 * 128, PT, 128, 128, 128, 128, 4, PL_PT, (size_t)128 * 128);
  tp(mix_W, mixWT, 12288, 96, 12288, 96, 1, (size_t)96 * 12288, (size_t)96 * 12288);
  cpb(adapt, adb, 19200 * 128, (size_t)19200 * 128);
  cpb(tod_tab, ttb, 288 * 128, (size_t)288 * 128);
  cpb(dow_tab, ddb, 7 * 128, (size_t)7 * 128);
  calc_vecs<<<1, 128, 0, stream>>>(emb_W, emb_b, proj_W, proj_b, vecs);
  concat_qkvb<<<(3 * 384 + 127) / 128, 128, 0, stream>>>(Lbq, Lbk, Lbv, qkvb);

  // ---- stage 1: static embedding pieces (dual -> fp32) ----
  gd(adb, (size_t)19200 * 128, P2T, PL_PT, nullptr, adP, nullptr, 0, 19200, 128, 128);
  gd(ttb, (size_t)288 * 128, P3T, PL_PT, nullptr, ttP, nullptr, 0, 288, 128, 128);
  gd(ddb, (size_t)7 * 128, P4T, PL_PT, nullptr, ddP, nullptr, 0, 7, 128, 128);

  // ---- stage 2: spatial transformer block (800 rows, S=1), dual ----
  xs_build<<<RSEQ, 128, 0, stream>>>(x_enc, stats, xsb, SPL);
  gd(xsb, SPL, spWt, 128 * 128, nullptr, nullptr, sp0b, SPL, RSEQ, 128, 128);
  gd(sp0b, SPL, spWqT, 128 * 128, sp_bq, spq, nullptr, 0, RSEQ, 128, 128);
  gd(sp0b, SPL, spWkT, 128 * 128, sp_bk, spk, nullptr, 0, RSEQ, 128, 128);
  gd(sp0b, SPL, spWvT, 128 * 128, sp_bv, spv, nullptr, 0, RSEQ, 128, 128);
  sp_perf<<<RSEQ, 128, 0, stream>>>(spq, spk, spv, sp_proj, spaob, SPL);
  gd(spaob, SPL, spWoT, 128 * 128, sp_bo, spR, nullptr, 0, RSEQ, 128, 128);
  ln_fused<<<RSEQ / 4, 256, 0, stream>>>(sp0b, SPL, spR, 128, nullptr, sp_l2g, sp_l2b, spx2b, SPL, RSEQ);
  gate_topk<<<(RSEQ * 4 + 255) / 256, 256, 0, stream>>>(spx2b, SPL, sp_gate, Gsp, RSEQ);
  for (int e = 0; e < 4; e++) {
    dim3 g1g((RSEQ + 127) / 128, 4, 1);
    gemm_bf16<1, 1, 0><<<g1g, 256, 0, stream>>>(spx2b, SPL, spW1T + (size_t)e * 512 * 128,
        (size_t)4 * 512 * 128, sp_b1 + e * 512, nullptr, Hsp, (size_t)RSEQ * 512,
        RSEQ, 128, 512, 128, nullptr, 0, 0);
    dim3 g2g((RSEQ + 127) / 128, 1, 1);
    gemm_bf16<2, 1, 0><<<g2g, 256, 0, stream>>>(Hsp, (size_t)RSEQ * 512,
        spW2T + (size_t)e * 128 * 512, (size_t)4 * 128 * 512, sp_b2 + e * 128, spR, nullptr, 0,
        RSEQ, 512, 128, 512, Gsp, e, e > 0);
  }
  ln_fused<<<RSEQ / 4, 256, 0, stream>>>(spx2b, SPL, spR, 128, nullptr, sp_l3g, sp_l3b, spob, SPL, RSEQ);
  gd(spob, SPL, P5T, PL_PT, nullptr, spP, nullptr, 0, RSEQ, 128, 128);

  // ---- stage 3: build xe0 (dual) ----
  embed_combine<<<Tt, 128, 0, stream>>>(x_enc, x_mark, stats, vecs, adP, ttP, ddP, spP, XB, PT128);

  // ---- stage 4: 3 transformer layers ----
  for (int i = 0; i < 3; i++) {
    for (int c = 0; c < 2; c++) {
      const u16* XBc = XB + (size_t)c * CH * 128;      // lo plane at +PT128 relative to XBc
      {
        dim3 g((CH + 127) / 128, 3, 1);
        gemm_bf16<0, 1, 0><<<g, 256, 0, stream>>>(XBc, PT128, LWqkvT + (size_t)i * 384 * 128,
            QKVPL, qkvb + i * 384, QKVf, nullptr, 0, CH, 128, 384, 128, nullptr, 0, 0);
      }
      performer_attn2<<<(RSEQ / 2) * 4, 256, 0, stream>>>(QKVf, Lproj + i * 256, AOf);
      {
        dim3 g((CH + 127) / 128, 1, 1);
        gemm_bf16<0, 1, 1><<<g, 256, 0, stream>>>((const u16*)AOf, 0,
            LWoT + (size_t)i * 128 * 128, WOPL, Lbo + i * 128, Rb + (size_t)c * CH * 128,
            nullptr, 0, CH, 128, 128, 128, nullptr, 0, 0);
      }
    }
    ln_fused<<<Tt / 4, 256, 0, stream>>>(XB, PT128, Rb, 128, nullptr,
                                         Ll2g + i * 128, Ll2b + i * 128, X2B, PT128, Tt);
    gate_topk<<<(Tt * 4 + 255) / 256, 256, 0, stream>>>(X2B, PT128, Lgate + i * 512, Gt, Tt);
    moe_zero_counts<<<1, 64, 0, stream>>>(mcnt);
    moe_fill<<<(Tt + 255) / 256, 256, 0, stream>>>(Gt, mcnt, midx, jsarr, Tt);
    // fused MoE FFN v2 (64 tokens/block, ns-chunked, no full-H): compact non-atomic output
    moe_ffn<<<dim3((Tt + MT - 1) / MT, 4), 256, 0, stream>>>(
        X2B, LW1T + (size_t)i * 4 * 512 * 128, LW2T + (size_t)i * 4 * 128 * 512,
        Lb1 + i * 4 * 512, Lb2 + i * 4 * 128, Gt, midx, mcnt, jsarr, Yc);
    // ln3 consumes Yc's two slots per token directly (combine fused)
    ln_fused<<<Tt / 4, 256, 0, stream>>>(X2B, PT128, Yc, 256, Yc + 128,
                                         Ll3g + i * 128, Ll3b + i * 128, XB, PT128, Tt);
  }

  // ---- stage 5: mix head (dual, split-K atomic) + denorm ----
  zero_f32<<<(RSEQ * 96 + 255) / 256, 256, 0, stream>>>(mixC, RSEQ * 96);
  {
    dim3 g((RSEQ + 127) / 128, 1, 16);  // 16 K-slices of 768
    gemm_bf16<3, 1, 0><<<g, 256, 0, stream>>>(XB, PT128, mixWT, (size_t)96 * 12288, nullptr,
        mixC, nullptr, 0, RSEQ, 12288, 96, 768, nullptr, 0, 0);
  }
  final_out<<<(Bb * PREDp * Nn + 255) / 256, 256, 0, stream>>>(mixC, mix_b, stats, (float*)d_out);
}